// Round 1
// baseline (3555.399 us; speedup 1.0000x reference)
//
#include <hip/hip_runtime.h>
#include <cmath>

#pragma clang fp contract(off)

#define NSAVE 101
#define NSUB  20
#define NCTRL 10

// np-faithful pow for the exponents that actually occur (uniform runtime branch).
// p==1 -> x (exact); p==2 -> x*x (correctly rounded); p==2.5 -> x^2*sqrt(x) in
// double, rounded once to f32 (matches correctly-rounded CPU powf for all
// practical inputs, incl. x<0 -> NaN via sqrt, x=0 -> 0, NaN propagation).
__device__ __forceinline__ float pow_np(float x, float p) {
    if (p == 1.0f) return x;
    if (p == 2.0f) return x * x;
    if (p == 2.5f) {
        double xd = (double)x;
        return (float)((xd * xd) * sqrt(xd));
    }
    return powf(x, p);
}

__global__ __launch_bounds__(256) void toggle_tsit5_kernel(
    const float* __restrict__ init,
    const float* __restrict__ useq,
    const float* __restrict__ params,
    float* __restrict__ out,
    int B)
{
    const int b = blockIdx.x * blockDim.x + threadIdx.x;

    // times = linspace(0,100,101): exact small integers in f32
    if (b < NSAVE) out[(size_t)B * 222 + b] = (float)b;
    if (b >= B) return;

    const float iptg_max = params[0];
    const float K        = params[1];
    const float n_iptg   = params[2];
    const float a1       = params[3];
    const float a2       = params[4];
    const float n_ab     = params[5];
    const float n_ba     = params[6];

    // clip + emit u output (B,10,2)
    const float* ub   = useq + (size_t)b * (NCTRL * 2);
    float*       uout = out + (size_t)B * 202 + (size_t)b * (NCTRL * 2);
    #pragma unroll
    for (int i = 0; i < NCTRL * 2; ++i) {
        float v = ub[i];
        v = fminf(fmaxf(v, 0.0f), 1.0f);
        uout[i] = v;
    }

    float A  = init[(size_t)b * 2 + 0];
    float Bc = init[(size_t)b * 2 + 1];
    float* ys = out + (size_t)b * 202;
    int bad = 0;
    {
        float wA = A, wB = Bc;
        if (!__builtin_isfinite(wA)) { wA = 0.0f; ++bad; }
        if (!__builtin_isfinite(wB)) { wB = 0.0f; ++bad; }
        ys[0] = wA; ys[1] = wB;
    }

    // h and stage-time offsets: replicate JAX weak-type demotion:
    // offsets computed as double products, rounded once to f32.
    const float h    = 0.05f;
    const float off2 = (float)(0.161 * 0.05);
    const float off3 = (float)(0.327 * 0.05);
    const float off4 = (float)(0.9 * 0.05);
    const float off5 = (float)(0.9800255409045097 * 0.05);

    const float A21f = 0.161f;
    const float A31f = -0.008480655492356989f, A32f = 0.335480655492357f;
    const float A41f = 2.8971530571054935f,  A42f = -6.359448489975075f,  A43f = 4.3622954328695815f;
    const float A51f = 5.325864828439257f,   A52f = -11.748883564062828f, A53f = 7.4955393428898365f, A54f = -0.09249506636175525f;
    const float A61f = 5.86145544294642f,    A62f = -12.92096931784711f,  A63f = 8.159367898576159f,  A64f = -0.071584973281401f, A65f = -0.028269050394068383f;
    const float B1f = 0.09646076681806523f, B2f = 0.01f, B3f = 0.4798896504144996f;
    const float B4f = 1.379008574103742f,   B5f = -3.290069515436081f, B6f = 2.324710524099774f;

    // per-control-interval denominator cache: (i/K)^n_iptg is constant per idx,
    // and idx is grid-uniform per stage (t identical across lanes) -> the
    // recompute branch is uniform and rare (~once per 200 substeps).
    int   cidx = -1;
    float denA = 1.0f, denB = 1.0f;

    auto vf = [&](float tst, float As, float Bs, float& dA, float& dB) {
        int idx = (int)floorf(tst / 10.0f);
        idx = idx < 0 ? 0 : (idx > NCTRL - 1 ? NCTRL - 1 : idx);
        if (idx != cidx) {
            cidx = idx;
            float u0 = fminf(fmaxf(ub[idx * 2 + 0], 0.0f), 1.0f);
            float u1 = fminf(fmaxf(ub[idx * 2 + 1], 0.0f), 1.0f);
            float iA = u0 * iptg_max;
            float iB = u1 * iptg_max;
            denA = 1.0f + pow_np(iA / K, n_iptg);
            denB = 1.0f + pow_np(iB / K, n_iptg);
        }
        float A_eff = As / denA;
        float B_eff = Bs / denB;
        float pB = pow_np(B_eff, n_ab);
        float pA = pow_np(A_eff, n_ba);
        dA = a1 / (1.0f + pB) - As;
        dB = a2 / (1.0f + pA) - Bs;
    };

    #pragma unroll 1
    for (int iv = 0; iv < NSAVE - 1; ++iv) {
        float t = (float)iv;   // t0 = i * 1.0f, exact
        #pragma unroll 1
        for (int j = 0; j < NSUB; ++j) {
            float k1A, k1B, k2A, k2B, k3A, k3B, k4A, k4B, k5A, k5B, k6A, k6B;

            vf(t, A, Bc, k1A, k1B);

            float s2A = A21f * k1A;
            float s2B = A21f * k1B;
            vf(t + off2, A + h * s2A, Bc + h * s2B, k2A, k2B);

            float s3A = A31f * k1A + A32f * k2A;
            float s3B = A31f * k1B + A32f * k2B;
            vf(t + off3, A + h * s3A, Bc + h * s3B, k3A, k3B);

            float s4A = A41f * k1A + A42f * k2A + A43f * k3A;
            float s4B = A41f * k1B + A42f * k2B + A43f * k3B;
            vf(t + off4, A + h * s4A, Bc + h * s4B, k4A, k4B);

            float s5A = A51f * k1A + A52f * k2A + A53f * k3A + A54f * k4A;
            float s5B = A51f * k1B + A52f * k2B + A53f * k3B + A54f * k4B;
            vf(t + off5, A + h * s5A, Bc + h * s5B, k5A, k5B);

            float s6A = A61f * k1A + A62f * k2A + A63f * k3A + A64f * k4A + A65f * k5A;
            float s6B = A61f * k1B + A62f * k2B + A63f * k3B + A64f * k4B + A65f * k5B;
            vf(t + h, A + h * s6A, Bc + h * s6B, k6A, k6B);

            float sfA = B1f * k1A + B2f * k2A + B3f * k3A + B4f * k4A + B5f * k5A + B6f * k6A;
            float sfB = B1f * k1B + B2f * k2B + B3f * k3B + B4f * k4B + B5f * k5B + B6f * k6B;
            A  = A  + h * sfA;
            Bc = Bc + h * sfB;
            t  = t + h;
        }
        float wA = A, wB = Bc;
        if (!__builtin_isfinite(wA)) { wA = 0.0f; ++bad; }
        if (!__builtin_isfinite(wB)) { wB = 0.0f; ++bad; }
        ys[(size_t)(iv + 1) * 2 + 0] = wA;
        ys[(size_t)(iv + 1) * 2 + 1] = wB;
    }

    if (bad) atomicAdd(out + (size_t)B * 222 + NSAVE, (float)bad);
}

extern "C" void kernel_launch(void* const* d_in, const int* in_sizes, int n_in,
                              void* d_out, int out_size, void* d_ws, size_t ws_size,
                              hipStream_t stream) {
    const float* init   = (const float*)d_in[0];
    const float* useq   = (const float*)d_in[1];
    const float* params = (const float*)d_in[2];
    float* out = (float*)d_out;

    const int B = in_sizes[0] / 2;

    // zero the n_bad accumulator slot (graph-capture-safe async memset)
    hipMemsetAsync(out + (size_t)B * 222 + NSAVE, 0, sizeof(float), stream);

    const int block = 256;
    const int grid  = (B + block - 1) / block;
    hipLaunchKernelGGL(toggle_tsit5_kernel, dim3(grid), dim3(block), 0, stream,
                       init, useq, params, out, B);
}

// Round 2
// 2231.266 us; speedup vs baseline: 1.5934x; 1.5934x over previous
//
#include <hip/hip_runtime.h>
#include <cmath>

#pragma clang fp contract(off)

#define NSAVE 101
#define NSUB  20
#define NCTRL 10
#define IV_PER_K 10   // 100 save intervals / 10 control intervals

// np-faithful pow for the exponents that occur (wave-uniform runtime branch).
// p==1 -> x (exact); p==2 -> x*x (correctly rounded);
// p==2.5 -> (x*x)*sqrtf(x): ~1.5 ulp vs correctly-rounded powf. NaN/Inf/neg
// semantics match np.power (sqrtf(neg)=NaN propagates).
__device__ __forceinline__ float pow_np_f32(float x, float p) {
    if (p == 2.5f) return (x * x) * sqrtf(x);
    if (p == 1.0f) return x;
    if (p == 2.0f) return x * x;
    return powf(x, p);
}

__global__ __launch_bounds__(256) void toggle_tsit5_kernel(
    const float* __restrict__ init,
    const float* __restrict__ useq,
    const float* __restrict__ params,
    float* __restrict__ out,
    int B)
{
    const int b = blockIdx.x * blockDim.x + threadIdx.x;

    // times = linspace(0,100,101): exact small integers in f32
    if (b < NSAVE) out[(size_t)B * 222 + b] = (float)b;
    if (b >= B) return;

    const float iptg_max = params[0];
    const float K        = params[1];
    const float n_iptg   = params[2];
    const float a1       = params[3];
    const float a2       = params[4];
    const float n_ab     = params[5];
    const float n_ba     = params[6];

    // clip + emit u output (B,10,2), vectorized: both b*20-float offsets are 16B-aligned
    const float* ub   = useq + (size_t)b * (NCTRL * 2);
    float*       uout = out + (size_t)B * 202 + (size_t)b * (NCTRL * 2);
    #pragma unroll
    for (int i = 0; i < 5; ++i) {
        float4 v = reinterpret_cast<const float4*>(ub)[i];
        v.x = fminf(fmaxf(v.x, 0.0f), 1.0f);
        v.y = fminf(fmaxf(v.y, 0.0f), 1.0f);
        v.z = fminf(fmaxf(v.z, 0.0f), 1.0f);
        v.w = fminf(fmaxf(v.w, 0.0f), 1.0f);
        reinterpret_cast<float4*>(uout)[i] = v;
    }

    float A  = init[(size_t)b * 2 + 0];
    float Bc = init[(size_t)b * 2 + 1];
    float* ys = out + (size_t)b * 202;
    int bad = 0;
    {
        float wA = A, wB = Bc;
        if (!__builtin_isfinite(wA)) { wA = 0.0f; ++bad; }
        if (!__builtin_isfinite(wB)) { wB = 0.0f; ++bad; }
        *reinterpret_cast<float2*>(&ys[0]) = make_float2(wA, wB);
    }

    const float h = 0.05f;

    const float A21f = 0.161f;
    const float A31f = -0.008480655492356989f, A32f = 0.335480655492357f;
    const float A41f = 2.8971530571054935f,  A42f = -6.359448489975075f,  A43f = 4.3622954328695815f;
    const float A51f = 5.325864828439257f,   A52f = -11.748883564062828f, A53f = 7.4955393428898365f, A54f = -0.09249506636175525f;
    const float A61f = 5.86145544294642f,    A62f = -12.92096931784711f,  A63f = 8.159367898576159f,  A64f = -0.071584973281401f, A65f = -0.028269050394068383f;
    const float B1f = 0.09646076681806523f, B2f = 0.01f, B3f = 0.4798896504144996f;
    const float B4f = 1.379008574103742f,   B5f = -3.290069515436081f, B6f = 2.324710524099774f;

    // per-control-group denominators (exact, matches reference recompute) and
    // their reciprocals (the per-eval mul-by-recip is the ~1ulp gamble)
    auto mk_den = [&](int k, float& dA_, float& dB_) {
        float u0 = fminf(fmaxf(ub[k * 2 + 0], 0.0f), 1.0f);
        float u1 = fminf(fmaxf(ub[k * 2 + 1], 0.0f), 1.0f);
        float xA = (u0 * iptg_max) / K;
        float xB = (u1 * iptg_max) / K;
        dA_ = 1.0f + pow_np_f32(xA, n_iptg);
        dB_ = 1.0f + pow_np_f32(xB, n_iptg);
    };

    // vf with hoisted denominators; t no longer needed inside
    auto vf = [&](float rdA, float rdB, float As, float Bs, float& dA, float& dB) {
        float A_eff = As * rdA;
        float B_eff = Bs * rdB;
        float pB = pow_np_f32(B_eff, n_ab);
        float pA = pow_np_f32(A_eff, n_ba);
        dA = a1 / (1.0f + pB) - As;   // IEEE divides kept as accuracy anchor
        dB = a2 / (1.0f + pA) - Bs;
    };

    float denA, denB;
    mk_den(0, denA, denB);
    float rdenA = 1.0f / denA, rdenB = 1.0f / denB;

    #pragma unroll 1
    for (int k = 0; k < NCTRL; ++k) {
        // dens for the NEXT control group (for the stage-6 boundary crossing);
        // k==9: clip keeps idx=9 -> same dens
        int kn = (k < NCTRL - 1) ? (k + 1) : k;
        float denA_nx, denB_nx;
        mk_den(kn, denA_nx, denB_nx);
        float rdenA_nx = 1.0f / denA_nx, rdenB_nx = 1.0f / denB_nx;
        const float bnd = 10.0f * (float)(k + 1);

        #pragma unroll 1
        for (int iv2 = 0; iv2 < IV_PER_K; ++iv2) {
            const int iv = k * IV_PER_K + iv2;
            float t = (float)iv;   // exact
            #pragma unroll 1
            for (int j = 0; j < NSUB; ++j) {
                // stage-6 control index: idx==k for all stages except possibly
                // stage 6 of the very last substep of the group, where
                // floor((t+h)/10.0f) == k+1  <=>  t+h >= 10(k+1)  (exact:
                // f32 ulp near 10k exceeds the divide round-up window)
                bool nx = (iv2 == IV_PER_K - 1) && (j == NSUB - 1) && (t + 0.05f >= bnd);
                float rdA6 = nx ? rdenA_nx : rdenA;
                float rdB6 = nx ? rdenB_nx : rdenB;

                float k1A, k1B, k2A, k2B, k3A, k3B, k4A, k4B, k5A, k5B, k6A, k6B;

                vf(rdenA, rdenB, A, Bc, k1A, k1B);

                float s2A = A21f * k1A;
                float s2B = A21f * k1B;
                vf(rdenA, rdenB, A + h * s2A, Bc + h * s2B, k2A, k2B);

                float s3A = A31f * k1A + A32f * k2A;
                float s3B = A31f * k1B + A32f * k2B;
                vf(rdenA, rdenB, A + h * s3A, Bc + h * s3B, k3A, k3B);

                float s4A = A41f * k1A + A42f * k2A + A43f * k3A;
                float s4B = A41f * k1B + A42f * k2B + A43f * k3B;
                vf(rdenA, rdenB, A + h * s4A, Bc + h * s4B, k4A, k4B);

                float s5A = A51f * k1A + A52f * k2A + A53f * k3A + A54f * k4A;
                float s5B = A51f * k1B + A52f * k2B + A53f * k3B + A54f * k4B;
                vf(rdenA, rdenB, A + h * s5A, Bc + h * s5B, k5A, k5B);

                float s6A = A61f * k1A + A62f * k2A + A63f * k3A + A64f * k4A + A65f * k5A;
                float s6B = A61f * k1B + A62f * k2B + A63f * k3B + A64f * k4B + A65f * k5B;
                vf(rdA6, rdB6, A + h * s6A, Bc + h * s6B, k6A, k6B);

                float sfA = B1f * k1A + B2f * k2A + B3f * k3A + B4f * k4A + B5f * k5A + B6f * k6A;
                float sfB = B1f * k1B + B2f * k2B + B3f * k3B + B4f * k4B + B5f * k5B + B6f * k6B;
                A  = A  + h * sfA;
                Bc = Bc + h * sfB;
                t  = t + h;   // bit-exact reference t accumulation
            }
            float wA = A, wB = Bc;
            if (!__builtin_isfinite(wA)) { wA = 0.0f; ++bad; }
            if (!__builtin_isfinite(wB)) { wB = 0.0f; ++bad; }
            *reinterpret_cast<float2*>(&ys[(size_t)(iv + 1) * 2]) = make_float2(wA, wB);
        }

        denA = denA_nx; denB = denB_nx;
        rdenA = rdenA_nx; rdenB = rdenB_nx;
    }

    if (bad) atomicAdd(out + (size_t)B * 222 + NSAVE, (float)bad);
}

extern "C" void kernel_launch(void* const* d_in, const int* in_sizes, int n_in,
                              void* d_out, int out_size, void* d_ws, size_t ws_size,
                              hipStream_t stream) {
    const float* init   = (const float*)d_in[0];
    const float* useq   = (const float*)d_in[1];
    const float* params = (const float*)d_in[2];
    float* out = (float*)d_out;

    const int B = in_sizes[0] / 2;

    // zero the n_bad accumulator slot (graph-capture-safe async memset)
    hipMemsetAsync(out + (size_t)B * 222 + NSAVE, 0, sizeof(float), stream);

    const int block = 256;
    const int grid  = (B + block - 1) / block;
    hipLaunchKernelGGL(toggle_tsit5_kernel, dim3(grid), dim3(block), 0, stream,
                       init, useq, params, out, B);
}

// Round 3
// 1597.158 us; speedup vs baseline: 2.2261x; 1.3970x over previous
//
#include <hip/hip_runtime.h>
#include <cmath>

#pragma clang fp contract(off)

#define NSAVE 101
#define NSUB  20
#define NCTRL 10
#define IV_PER_K 10   // 100 save intervals / 10 control intervals

// np-faithful pow for the exponents that occur (wave-uniform runtime branch).
__device__ __forceinline__ float pow_np_f32(float x, float p) {
    if (p == 2.5f) return (x * x) * sqrtf(x);
    if (p == 1.0f) return x;
    if (p == 2.0f) return x * x;
    return powf(x, p);
}

// swap values between even/odd lane neighbors: quad_perm(1,0,3,2) = 0xB1.
// Single VALU DPP instruction; both lanes of a pair are always convergent here.
__device__ __forceinline__ float swap_pair(float v) {
    int r = __builtin_amdgcn_update_dpp(0, __float_as_int(v),
                                        0xB1, 0xF, 0xF, true);
    return __int_as_float(r);
}

__global__ __launch_bounds__(256) void toggle_tsit5_kernel(
    const float* __restrict__ init,
    const float* __restrict__ useq,
    const float* __restrict__ params,
    float* __restrict__ out,
    int B)
{
    const int tid = blockIdx.x * blockDim.x + threadIdx.x;
    const int NT  = 2 * B;

    // times = linspace(0,100,101): exact small integers in f32
    if (tid < NSAVE) out[(size_t)B * 222 + tid] = (float)tid;
    if (tid >= NT) return;

    const float iptg_max = params[0];
    const float K        = params[1];
    const float n_iptg   = params[2];
    const float a1       = params[3];
    const float a2       = params[4];
    const float n_ab     = params[5];
    const float n_ba     = params[6];

    // u clip+copy, flat: thread tid handles floats [tid*10, tid*10+10)
    {
        const float* src = useq + (size_t)tid * 10;
        float*       dst = out + (size_t)B * 202 + (size_t)tid * 10;
        #pragma unroll
        for (int i = 0; i < 5; ++i) {
            float2 v = reinterpret_cast<const float2*>(src)[i];
            v.x = fminf(fmaxf(v.x, 0.0f), 1.0f);
            v.y = fminf(fmaxf(v.y, 0.0f), 1.0f);
            reinterpret_cast<float2*>(dst)[i] = v;
        }
    }

    const float h = 0.05f;
    const float A21f = 0.161f;
    const float A31f = -0.008480655492356989f, A32f = 0.335480655492357f;
    const float A41f = 2.8971530571054935f,  A42f = -6.359448489975075f,  A43f = 4.3622954328695815f;
    const float A51f = 5.325864828439257f,   A52f = -11.748883564062828f, A53f = 7.4955393428898365f, A54f = -0.09249506636175525f;
    const float A61f = 5.86145544294642f,    A62f = -12.92096931784711f,  A63f = 8.159367898576159f,  A64f = -0.071584973281401f, A65f = -0.028269050394068383f;
    const float B1f = 0.09646076681806523f, B2f = 0.01f, B3f = 0.4798896504144996f;
    const float B4f = 1.379008574103742f,   B5f = -3.290069515436081f, B6f = 2.324710524099774f;

    const bool special = (n_iptg == 2.0f) && (n_ab == 2.5f) && (n_ba == 1.0f);

    if (special) {
        // ---- lane-split path: even lane = A component, odd lane = B component ----
        const int  p   = tid >> 1;
        const int  c   = tid & 1;
        const bool isB = (c != 0);
        const float num = isB ? a2 : a1;   // dA uses a1, dB uses a2

        const float* ub = useq + (size_t)p * (NCTRL * 2);
        float x = init[(size_t)tid];       // == init[p*2+c]
        float* ys = out + (size_t)p * 202 + c;
        int bad = 0;
        {
            float w = x;
            if (!__builtin_isfinite(w)) { w = 0.0f; ++bad; }
            ys[0] = w;
        }

        // own-component control denominator reciprocal for group k (n_iptg=2)
        auto mk_rd = [&](int k) -> float {
            float u  = fminf(fmaxf(ub[k * 2 + c], 0.0f), 1.0f);
            float xx = (u * iptg_max) / K;
            float den = 1.0f + xx * xx;
            return 1.0f / den;
        };

        // one component's derivative; cross term arrives via DPP pair swap.
        // B-lane exports pow(B_eff,2.5), A-lane exports A_eff (pow(.,1)).
        auto deriv = [&](float rd_, float xs) -> float {
            float xe = xs * rd_;
            float pv = (xe * xe) * sqrtf(xe);
            float own = isB ? pv : xe;
            float recv = swap_pair(own);
            return num / (1.0f + recv) - xs;   // IEEE divide: accuracy anchor
        };

        float rd = mk_rd(0);
        #pragma unroll 1
        for (int k = 0; k < NCTRL; ++k) {
            int kn = (k < NCTRL - 1) ? (k + 1) : k;
            float rd_nx = mk_rd(kn);
            const float bnd = 10.0f * (float)(k + 1);

            #pragma unroll 1
            for (int iv2 = 0; iv2 < IV_PER_K; ++iv2) {
                const int iv = k * IV_PER_K + iv2;
                float t = (float)iv;   // exact
                #pragma unroll 1
                for (int j = 0; j < NSUB; ++j) {
                    // stage-6 control index can cross the group boundary only on
                    // the last substep: floor((t+h)/10)==k+1 <=> t+h >= 10(k+1)
                    bool nx = (iv2 == IV_PER_K - 1) && (j == NSUB - 1) && (t + 0.05f >= bnd);
                    float rd6 = nx ? rd_nx : rd;

                    float k1 = deriv(rd,  x);
                    float k2 = deriv(rd,  x + h * (A21f * k1));
                    float k3 = deriv(rd,  x + h * (A31f * k1 + A32f * k2));
                    float k4 = deriv(rd,  x + h * (A41f * k1 + A42f * k2 + A43f * k3));
                    float k5 = deriv(rd,  x + h * (A51f * k1 + A52f * k2 + A53f * k3 + A54f * k4));
                    float k6 = deriv(rd6, x + h * (A61f * k1 + A62f * k2 + A63f * k3 + A64f * k4 + A65f * k5));

                    x = x + h * (B1f * k1 + B2f * k2 + B3f * k3 + B4f * k4 + B5f * k5 + B6f * k6);
                    t = t + h;   // bit-exact reference t accumulation
                }
                float w = x;
                if (!__builtin_isfinite(w)) { w = 0.0f; ++bad; }
                ys[(size_t)(iv + 1) * 2] = w;
            }
            rd = rd_nx;
        }

        if (bad) atomicAdd(out + (size_t)B * 222 + NSAVE, (float)bad);

    } else if (tid < B) {
        // ---- generic fallback: one thread per trajectory, both components ----
        const int b = tid;
        const float* ub = useq + (size_t)b * (NCTRL * 2);
        float A  = init[(size_t)b * 2 + 0];
        float Bc = init[(size_t)b * 2 + 1];
        float* ys = out + (size_t)b * 202;
        int bad = 0;
        {
            float wA = A, wB = Bc;
            if (!__builtin_isfinite(wA)) { wA = 0.0f; ++bad; }
            if (!__builtin_isfinite(wB)) { wB = 0.0f; ++bad; }
            ys[0] = wA; ys[1] = wB;
        }

        auto mk_den = [&](int k, float& dA_, float& dB_) {
            float u0 = fminf(fmaxf(ub[k * 2 + 0], 0.0f), 1.0f);
            float u1 = fminf(fmaxf(ub[k * 2 + 1], 0.0f), 1.0f);
            float xA = (u0 * iptg_max) / K;
            float xB = (u1 * iptg_max) / K;
            dA_ = 1.0f + pow_np_f32(xA, n_iptg);
            dB_ = 1.0f + pow_np_f32(xB, n_iptg);
        };
        auto vf = [&](float rdA, float rdB, float As, float Bs, float& dA, float& dB) {
            float A_eff = As * rdA;
            float B_eff = Bs * rdB;
            float pB = pow_np_f32(B_eff, n_ab);
            float pA = pow_np_f32(A_eff, n_ba);
            dA = a1 / (1.0f + pB) - As;
            dB = a2 / (1.0f + pA) - Bs;
        };

        float denA, denB;
        mk_den(0, denA, denB);
        float rdenA = 1.0f / denA, rdenB = 1.0f / denB;

        #pragma unroll 1
        for (int k = 0; k < NCTRL; ++k) {
            int kn = (k < NCTRL - 1) ? (k + 1) : k;
            float denA_nx, denB_nx;
            mk_den(kn, denA_nx, denB_nx);
            float rdenA_nx = 1.0f / denA_nx, rdenB_nx = 1.0f / denB_nx;
            const float bnd = 10.0f * (float)(k + 1);

            #pragma unroll 1
            for (int iv2 = 0; iv2 < IV_PER_K; ++iv2) {
                const int iv = k * IV_PER_K + iv2;
                float t = (float)iv;
                #pragma unroll 1
                for (int j = 0; j < NSUB; ++j) {
                    bool nx = (iv2 == IV_PER_K - 1) && (j == NSUB - 1) && (t + 0.05f >= bnd);
                    float rdA6 = nx ? rdenA_nx : rdenA;
                    float rdB6 = nx ? rdenB_nx : rdenB;

                    float k1A, k1B, k2A, k2B, k3A, k3B, k4A, k4B, k5A, k5B, k6A, k6B;
                    vf(rdenA, rdenB, A, Bc, k1A, k1B);
                    vf(rdenA, rdenB, A + h * (A21f * k1A), Bc + h * (A21f * k1B), k2A, k2B);
                    vf(rdenA, rdenB, A + h * (A31f * k1A + A32f * k2A), Bc + h * (A31f * k1B + A32f * k2B), k3A, k3B);
                    vf(rdenA, rdenB, A + h * (A41f * k1A + A42f * k2A + A43f * k3A),
                                      Bc + h * (A41f * k1B + A42f * k2B + A43f * k3B), k4A, k4B);
                    vf(rdenA, rdenB, A + h * (A51f * k1A + A52f * k2A + A53f * k3A + A54f * k4A),
                                      Bc + h * (A51f * k1B + A52f * k2B + A53f * k3B + A54f * k4B), k5A, k5B);
                    vf(rdA6, rdB6,   A + h * (A61f * k1A + A62f * k2A + A63f * k3A + A64f * k4A + A65f * k5A),
                                      Bc + h * (A61f * k1B + A62f * k2B + A63f * k3B + A64f * k4B + A65f * k5B), k6A, k6B);

                    A  = A  + h * (B1f * k1A + B2f * k2A + B3f * k3A + B4f * k4A + B5f * k5A + B6f * k6A);
                    Bc = Bc + h * (B1f * k1B + B2f * k2B + B3f * k3B + B4f * k4B + B5f * k5B + B6f * k6B);
                    t  = t + h;
                }
                float wA = A, wB = Bc;
                if (!__builtin_isfinite(wA)) { wA = 0.0f; ++bad; }
                if (!__builtin_isfinite(wB)) { wB = 0.0f; ++bad; }
                ys[(size_t)(iv + 1) * 2 + 0] = wA;
                ys[(size_t)(iv + 1) * 2 + 1] = wB;
            }
            denA = denA_nx; denB = denB_nx;
            rdenA = rdenA_nx; rdenB = rdenB_nx;
        }

        if (bad) atomicAdd(out + (size_t)B * 222 + NSAVE, (float)bad);
    }
}

extern "C" void kernel_launch(void* const* d_in, const int* in_sizes, int n_in,
                              void* d_out, int out_size, void* d_ws, size_t ws_size,
                              hipStream_t stream) {
    const float* init   = (const float*)d_in[0];
    const float* useq   = (const float*)d_in[1];
    const float* params = (const float*)d_in[2];
    float* out = (float*)d_out;

    const int B = in_sizes[0] / 2;

    // zero the n_bad accumulator slot (graph-capture-safe async memset)
    hipMemsetAsync(out + (size_t)B * 222 + NSAVE, 0, sizeof(float), stream);

    const int block = 256;
    const int grid  = (2 * B + block - 1) / block;
    hipLaunchKernelGGL(toggle_tsit5_kernel, dim3(grid), dim3(block), 0, stream,
                       init, useq, params, out, B);
}

// Round 4
// 804.912 us; speedup vs baseline: 4.4171x; 1.9843x over previous
//
#include <hip/hip_runtime.h>
#include <cmath>

#pragma clang fp contract(off)

#define NSAVE 101
#define NSUB  20
#define NCTRL 10
#define IV_PER_K 10   // 100 save intervals / 10 control intervals

// np-faithful pow for the exponents that occur (wave-uniform runtime branch).
__device__ __forceinline__ float pow_np_f32(float x, float p) {
    if (p == 2.5f) return (x * x) * sqrtf(x);
    if (p == 1.0f) return x;
    if (p == 2.0f) return x * x;
    return powf(x, p);
}

// swap values between even/odd lane neighbors: quad_perm(1,0,3,2) = 0xB1.
// Single VALU DPP instruction; both lanes of a pair are always convergent here.
__device__ __forceinline__ float swap_pair(float v) {
    int r = __builtin_amdgcn_update_dpp(0, __float_as_int(v),
                                        0xB1, 0xF, 0xF, true);
    return __int_as_float(r);
}

__global__ __launch_bounds__(256) void toggle_tsit5_kernel(
    const float* __restrict__ init,
    const float* __restrict__ useq,
    const float* __restrict__ params,
    float* __restrict__ out,
    int B)
{
    const int tid = blockIdx.x * blockDim.x + threadIdx.x;
    const int NT  = 2 * B;

    // times = linspace(0,100,101): exact small integers in f32
    if (tid < NSAVE) out[(size_t)B * 222 + tid] = (float)tid;
    if (tid >= NT) return;

    const float iptg_max = params[0];
    const float K        = params[1];
    const float n_iptg   = params[2];
    const float a1       = params[3];
    const float a2       = params[4];
    const float n_ab     = params[5];
    const float n_ba     = params[6];

    // u clip+copy, flat: thread tid handles floats [tid*10, tid*10+10)
    {
        const float* src = useq + (size_t)tid * 10;
        float*       dst = out + (size_t)B * 202 + (size_t)tid * 10;
        #pragma unroll
        for (int i = 0; i < 5; ++i) {
            float2 v = reinterpret_cast<const float2*>(src)[i];
            v.x = fminf(fmaxf(v.x, 0.0f), 1.0f);
            v.y = fminf(fmaxf(v.y, 0.0f), 1.0f);
            reinterpret_cast<float2*>(dst)[i] = v;
        }
    }

    const float h = 0.05f;
    const float A21f = 0.161f;
    const float A31f = -0.008480655492356989f, A32f = 0.335480655492357f;
    const float A41f = 2.8971530571054935f,  A42f = -6.359448489975075f,  A43f = 4.3622954328695815f;
    const float A51f = 5.325864828439257f,   A52f = -11.748883564062828f, A53f = 7.4955393428898365f, A54f = -0.09249506636175525f;
    const float A61f = 5.86145544294642f,    A62f = -12.92096931784711f,  A63f = 8.159367898576159f,  A64f = -0.071584973281401f, A65f = -0.028269050394068383f;
    const float B1f = 0.09646076681806523f, B2f = 0.01f, B3f = 0.4798896504144996f;
    const float B4f = 1.379008574103742f,   B5f = -3.290069515436081f, B6f = 2.324710524099774f;

    const bool special = (n_iptg == 2.0f) && (n_ab == 2.5f) && (n_ba == 1.0f);

    if (special) {
        // ---- lane-split path: even lane = A component, odd lane = B component ----
        const int  p   = tid >> 1;
        const int  c   = tid & 1;
        const bool isB = (c != 0);
        const float num = isB ? a2 : a1;   // dA uses a1, dB uses a2

        const float* ub = useq + (size_t)p * (NCTRL * 2);
        float x = init[(size_t)tid];       // == init[p*2+c]
        float* ys = out + (size_t)p * 202 + c;
        int bad = 0;
        {
            float w = x;
            if (!__builtin_isfinite(w)) { w = 0.0f; ++bad; }
            ys[0] = w;
        }

        // own-component control denominator reciprocal for group k (n_iptg=2).
        // Off the hot chain (runs 10x total) -> keep IEEE ops here.
        auto mk_rd = [&](int k) -> float {
            float u  = fminf(fmaxf(ub[k * 2 + c], 0.0f), 1.0f);
            float xx = (u * iptg_max) / K;
            float den = 1.0f + xx * xx;
            return 1.0f / den;
        };

        // one component's derivative; cross term arrives via DPP pair swap.
        // B-lane exports pow(B_eff,2.5), A-lane exports A_eff (pow(.,1)).
        // Hot chain: raw v_sqrt_f32 / v_rcp_f32 (~1 ulp each) instead of the
        // IEEE expansions — per-eval noise comparable to R2's gamble, which
        // left absmax bit-identical. NaN/Inf semantics preserved.
        auto deriv = [&](float rd_, float xs) -> float {
            float xe = xs * rd_;
            float pv = (xe * xe) * __builtin_amdgcn_sqrtf(xe);
            float own = isB ? pv : xe;
            float recv = swap_pair(own);
            return num * __builtin_amdgcn_rcpf(1.0f + recv) - xs;
        };

        float rd = mk_rd(0);
        #pragma unroll 1
        for (int k = 0; k < NCTRL; ++k) {
            int kn = (k < NCTRL - 1) ? (k + 1) : k;
            float rd_nx = mk_rd(kn);
            const float bnd = 10.0f * (float)(k + 1);

            #pragma unroll 1
            for (int iv2 = 0; iv2 < IV_PER_K; ++iv2) {
                const int iv = k * IV_PER_K + iv2;
                float t = (float)iv;   // exact

                // substeps 0..18: control index provably constant (= k)
                #pragma unroll 1
                for (int j = 0; j < NSUB - 1; ++j) {
                    float k1 = deriv(rd, x);
                    float k2 = deriv(rd, x + h * (A21f * k1));
                    float k3 = deriv(rd, x + h * (A31f * k1 + A32f * k2));
                    float k4 = deriv(rd, x + h * (A41f * k1 + A42f * k2 + A43f * k3));
                    float k5 = deriv(rd, x + h * (A51f * k1 + A52f * k2 + A53f * k3 + A54f * k4));
                    float k6 = deriv(rd, x + h * (A61f * k1 + A62f * k2 + A63f * k3 + A64f * k4 + A65f * k5));
                    x = x + h * (B1f * k1 + B2f * k2 + B3f * k3 + B4f * k4 + B5f * k5 + B6f * k6);
                    t = t + h;   // bit-exact reference t accumulation
                }

                // peeled substep 19: stage-6 may cross the control boundary.
                // floor((t+h)/10)==k+1 <=> t+h >= 10(k+1) (exact near 10k)
                {
                    float rd6 = ((iv2 == IV_PER_K - 1) && (t + 0.05f >= bnd)) ? rd_nx : rd;
                    float k1 = deriv(rd, x);
                    float k2 = deriv(rd, x + h * (A21f * k1));
                    float k3 = deriv(rd, x + h * (A31f * k1 + A32f * k2));
                    float k4 = deriv(rd, x + h * (A41f * k1 + A42f * k2 + A43f * k3));
                    float k5 = deriv(rd, x + h * (A51f * k1 + A52f * k2 + A53f * k3 + A54f * k4));
                    float k6 = deriv(rd6, x + h * (A61f * k1 + A62f * k2 + A63f * k3 + A64f * k4 + A65f * k5));
                    x = x + h * (B1f * k1 + B2f * k2 + B3f * k3 + B4f * k4 + B5f * k5 + B6f * k6);
                }

                float w = x;
                if (!__builtin_isfinite(w)) { w = 0.0f; ++bad; }
                ys[(size_t)(iv + 1) * 2] = w;
            }
            rd = rd_nx;
        }

        if (bad) atomicAdd(out + (size_t)B * 222 + NSAVE, (float)bad);

    } else if (tid < B) {
        // ---- generic fallback: one thread per trajectory, both components ----
        const int b = tid;
        const float* ub = useq + (size_t)b * (NCTRL * 2);
        float A  = init[(size_t)b * 2 + 0];
        float Bc = init[(size_t)b * 2 + 1];
        float* ys = out + (size_t)b * 202;
        int bad = 0;
        {
            float wA = A, wB = Bc;
            if (!__builtin_isfinite(wA)) { wA = 0.0f; ++bad; }
            if (!__builtin_isfinite(wB)) { wB = 0.0f; ++bad; }
            ys[0] = wA; ys[1] = wB;
        }

        auto mk_den = [&](int k, float& dA_, float& dB_) {
            float u0 = fminf(fmaxf(ub[k * 2 + 0], 0.0f), 1.0f);
            float u1 = fminf(fmaxf(ub[k * 2 + 1], 0.0f), 1.0f);
            float xA = (u0 * iptg_max) / K;
            float xB = (u1 * iptg_max) / K;
            dA_ = 1.0f + pow_np_f32(xA, n_iptg);
            dB_ = 1.0f + pow_np_f32(xB, n_iptg);
        };
        auto vf = [&](float rdA, float rdB, float As, float Bs, float& dA, float& dB) {
            float A_eff = As * rdA;
            float B_eff = Bs * rdB;
            float pB = pow_np_f32(B_eff, n_ab);
            float pA = pow_np_f32(A_eff, n_ba);
            dA = a1 / (1.0f + pB) - As;
            dB = a2 / (1.0f + pA) - Bs;
        };

        float denA, denB;
        mk_den(0, denA, denB);
        float rdenA = 1.0f / denA, rdenB = 1.0f / denB;

        #pragma unroll 1
        for (int k = 0; k < NCTRL; ++k) {
            int kn = (k < NCTRL - 1) ? (k + 1) : k;
            float denA_nx, denB_nx;
            mk_den(kn, denA_nx, denB_nx);
            float rdenA_nx = 1.0f / denA_nx, rdenB_nx = 1.0f / denB_nx;
            const float bnd = 10.0f * (float)(k + 1);

            #pragma unroll 1
            for (int iv2 = 0; iv2 < IV_PER_K; ++iv2) {
                const int iv = k * IV_PER_K + iv2;
                float t = (float)iv;
                #pragma unroll 1
                for (int j = 0; j < NSUB; ++j) {
                    bool nx = (iv2 == IV_PER_K - 1) && (j == NSUB - 1) && (t + 0.05f >= bnd);
                    float rdA6 = nx ? rdenA_nx : rdenA;
                    float rdB6 = nx ? rdenB_nx : rdenB;

                    float k1A, k1B, k2A, k2B, k3A, k3B, k4A, k4B, k5A, k5B, k6A, k6B;
                    vf(rdenA, rdenB, A, Bc, k1A, k1B);
                    vf(rdenA, rdenB, A + h * (A21f * k1A), Bc + h * (A21f * k1B), k2A, k2B);
                    vf(rdenA, rdenB, A + h * (A31f * k1A + A32f * k2A), Bc + h * (A31f * k1B + A32f * k2B), k3A, k3B);
                    vf(rdenA, rdenB, A + h * (A41f * k1A + A42f * k2A + A43f * k3A),
                                      Bc + h * (A41f * k1B + A42f * k2B + A43f * k3B), k4A, k4B);
                    vf(rdenA, rdenB, A + h * (A51f * k1A + A52f * k2A + A53f * k3A + A54f * k4A),
                                      Bc + h * (A51f * k1B + A52f * k2B + A53f * k3B + A54f * k4B), k5A, k5B);
                    vf(rdA6, rdB6,   A + h * (A61f * k1A + A62f * k2A + A63f * k3A + A64f * k4A + A65f * k5A),
                                      Bc + h * (A61f * k1B + A62f * k2B + A63f * k3B + A64f * k4B + A65f * k5B), k6A, k6B);

                    A  = A  + h * (B1f * k1A + B2f * k2A + B3f * k3A + B4f * k4A + B5f * k5A + B6f * k6A);
                    Bc = Bc + h * (B1f * k1B + B2f * k2B + B3f * k3B + B4f * k4B + B5f * k5B + B6f * k6B);
                    t  = t + h;
                }
                float wA = A, wB = Bc;
                if (!__builtin_isfinite(wA)) { wA = 0.0f; ++bad; }
                if (!__builtin_isfinite(wB)) { wB = 0.0f; ++bad; }
                ys[(size_t)(iv + 1) * 2 + 0] = wA;
                ys[(size_t)(iv + 1) * 2 + 1] = wB;
            }
            denA = denA_nx; denB = denB_nx;
            rdenA = rdenA_nx; rdenB = rdenB_nx;
        }

        if (bad) atomicAdd(out + (size_t)B * 222 + NSAVE, (float)bad);
    }
}

extern "C" void kernel_launch(void* const* d_in, const int* in_sizes, int n_in,
                              void* d_out, int out_size, void* d_ws, size_t ws_size,
                              hipStream_t stream) {
    const float* init   = (const float*)d_in[0];
    const float* useq   = (const float*)d_in[1];
    const float* params = (const float*)d_in[2];
    float* out = (float*)d_out;

    const int B = in_sizes[0] / 2;

    // zero the n_bad accumulator slot (graph-capture-safe async memset)
    hipMemsetAsync(out + (size_t)B * 222 + NSAVE, 0, sizeof(float), stream);

    const int block = 256;
    const int grid  = (2 * B + block - 1) / block;
    hipLaunchKernelGGL(toggle_tsit5_kernel, dim3(grid), dim3(block), 0, stream,
                       init, useq, params, out, B);
}

// Round 5
// 622.165 us; speedup vs baseline: 5.7146x; 1.2937x over previous
//
#include <hip/hip_runtime.h>
#include <cmath>
#include <type_traits>

#pragma clang fp contract(off)

#define NSAVE 101
#define NSUB  20
#define NCTRL 10
#define IV_PER_K 10   // 100 save intervals / 10 control intervals

// np-faithful pow for the exponents that occur (generic fallback path only).
__device__ __forceinline__ float pow_np_f32(float x, float p) {
    if (p == 2.5f) return (x * x) * sqrtf(x);
    if (p == 1.0f) return x;
    if (p == 2.0f) return x * x;
    return powf(x, p);
}

// swap values between even/odd lane neighbors: quad_perm(1,0,3,2) = 0xB1.
__device__ __forceinline__ float swap_pair(float v) {
    int r = __builtin_amdgcn_update_dpp(0, __float_as_int(v),
                                        0xB1, 0xF, 0xF, true);
    return __int_as_float(r);
}

// h-premultiplied Butcher constants (double product, rounded once)
#define HCF(x) ((float)(0.05 * (x)))
__device__ constexpr float HA21 = HCF(0.161);
__device__ constexpr float HA31 = HCF(-0.008480655492356989), HA32 = HCF(0.335480655492357);
__device__ constexpr float HA41 = HCF(2.8971530571054935),  HA42 = HCF(-6.359448489975075),  HA43 = HCF(4.3622954328695815);
__device__ constexpr float HA51 = HCF(5.325864828439257),   HA52 = HCF(-11.748883564062828), HA53 = HCF(7.4955393428898365), HA54 = HCF(-0.09249506636175525);
__device__ constexpr float HA61 = HCF(5.86145544294642),    HA62 = HCF(-12.92096931784711),  HA63 = HCF(8.159367898576159),  HA64 = HCF(-0.071584973281401), HA65 = HCF(-0.028269050394068383);
__device__ constexpr float HB1 = HCF(0.09646076681806523), HB2 = HCF(0.01), HB3 = HCF(0.4798896504144996);
__device__ constexpr float HB4 = HCF(1.379008574103742),   HB5 = HCF(-3.290069515436081), HB6 = HCF(2.324710524099774);

__global__ __launch_bounds__(256) void toggle_tsit5_kernel(
    const float* __restrict__ init,
    const float* __restrict__ useq,
    const float* __restrict__ params,
    float* __restrict__ out,
    int B)
{
    const int tid = blockIdx.x * blockDim.x + threadIdx.x;
    const int NT  = 2 * B;

    // times = linspace(0,100,101): exact small integers in f32
    if (tid < NSAVE) out[(size_t)B * 222 + tid] = (float)tid;
    if (tid >= NT) return;

    const float iptg_max = params[0];
    const float K        = params[1];
    const float n_iptg   = params[2];
    const float a1       = params[3];
    const float a2       = params[4];
    const float n_ab     = params[5];
    const float n_ba     = params[6];

    // u clip+copy, flat: thread tid handles floats [tid*10, tid*10+10)
    {
        const float* src = useq + (size_t)tid * 10;
        float*       dst = out + (size_t)B * 202 + (size_t)tid * 10;
        #pragma unroll
        for (int i = 0; i < 5; ++i) {
            float2 v = reinterpret_cast<const float2*>(src)[i];
            v.x = fminf(fmaxf(v.x, 0.0f), 1.0f);
            v.y = fminf(fmaxf(v.y, 0.0f), 1.0f);
            reinterpret_cast<float2*>(dst)[i] = v;
        }
    }

    const bool special = (n_iptg == 2.0f) && (n_ab == 2.5f) && (n_ba == 1.0f);

    if (special) {
        // ---- lane-split q-form path: even lane = A component, odd = B ----
        const int  p   = tid >> 1;
        const int  c   = tid & 1;
        const bool isB = (c != 0);
        const float num = isB ? a2 : a1;

        const float* ub = useq + (size_t)p * (NCTRL * 2);
        float x0 = init[(size_t)tid];
        float* ys = out + (size_t)p * 202 + c;
        int bad = 0;
        {
            float w = x0;
            if (!__builtin_isfinite(w)) { w = 0.0f; ++bad; }
            ys[0] = w;
        }

        // own-component control denominator for group k (n_iptg=2), off hot path
        auto mk_den = [&](int k) -> float {
            float u  = fminf(fmaxf(ub[k * 2 + c], 0.0f), 1.0f);
            float xx = (u * iptg_max) / K;
            return 1.0f + xx * xx;
        };

        // stage export -> cross-lane -> reciprocal. B-lane exports 1+z^2.5
        // (fma-fused), A-lane exports 1+z; r = rcp(1 + other's value).
        auto stage_r = [&](float zi) -> float {
            float pb = __builtin_fmaf(zi * zi, __builtin_amdgcn_sqrtf(zi), 1.0f);
            float pa = zi + 1.0f;
            float ow = isB ? pb : pa;
            return __builtin_amdgcn_rcpf(swap_pair(ow));
        };

        float den = mk_den(0);
        float rd  = 1.0f / den;
        float z   = x0 * rd;           // scaled state: z = x * rd

        // per-group runtime constants: HAN = HA * (num*rd), HBN = HB * (num*rd)
        float HAN21, HAN31, HAN32, HAN41, HAN42, HAN43,
              HAN51, HAN52, HAN53, HAN54, HAN61, HAN62, HAN63, HAN64, HAN65;
        float HBN1, HBN2, HBN3, HBN4, HBN5, HBN6;
        auto rebuild = [&](float RN) {
            HAN21 = HA21 * RN;
            HAN31 = HA31 * RN; HAN32 = HA32 * RN;
            HAN41 = HA41 * RN; HAN42 = HA42 * RN; HAN43 = HA43 * RN;
            HAN51 = HA51 * RN; HAN52 = HA52 * RN; HAN53 = HA53 * RN; HAN54 = HA54 * RN;
            HAN61 = HA61 * RN; HAN62 = HA62 * RN; HAN63 = HA63 * RN; HAN64 = HA64 * RN; HAN65 = HA65 * RN;
            HBN1 = HB1 * RN; HBN2 = HB2 * RN; HBN3 = HB3 * RN;
            HBN4 = HB4 * RN; HBN5 = HB5 * RN; HBN6 = HB6 * RN;
        };
        rebuild(num * rd);

        // one Tsit5 substep in q-form. S6TAG: stage-6 input scaled by s6r
        // (control-boundary crossing uses next group's rd: w6 = z6*(den*rd_nx)).
        auto substep = [&](auto s6tag, float s6r) {
            float z1 = z;
            float r1 = stage_r(z1);

            float b2 = __builtin_fmaf(-HA21, z1, z1);
            float z2 = __builtin_fmaf(HAN21, r1, b2);
            float r2 = stage_r(z2);

            float b3 = __builtin_fmaf(-HA31, z1, z1);
            b3 = __builtin_fmaf(HAN31, r1, b3);
            b3 = __builtin_fmaf(-HA32, z2, b3);
            float z3 = __builtin_fmaf(HAN32, r2, b3);
            float r3 = stage_r(z3);

            float b4 = __builtin_fmaf(-HA41, z1, z1);
            b4 = __builtin_fmaf(HAN41, r1, b4);
            b4 = __builtin_fmaf(-HA42, z2, b4);
            b4 = __builtin_fmaf(HAN42, r2, b4);
            b4 = __builtin_fmaf(-HA43, z3, b4);
            float z4 = __builtin_fmaf(HAN43, r3, b4);
            float r4 = stage_r(z4);

            float b5 = __builtin_fmaf(-HA51, z1, z1);
            b5 = __builtin_fmaf(HAN51, r1, b5);
            b5 = __builtin_fmaf(-HA52, z2, b5);
            b5 = __builtin_fmaf(HAN52, r2, b5);
            b5 = __builtin_fmaf(-HA53, z3, b5);
            b5 = __builtin_fmaf(HAN53, r3, b5);
            b5 = __builtin_fmaf(-HA54, z4, b5);
            float z5 = __builtin_fmaf(HAN54, r4, b5);
            float r5 = stage_r(z5);

            float b6 = __builtin_fmaf(-HA61, z1, z1);
            b6 = __builtin_fmaf(HAN61, r1, b6);
            b6 = __builtin_fmaf(-HA62, z2, b6);
            b6 = __builtin_fmaf(HAN62, r2, b6);
            b6 = __builtin_fmaf(-HA63, z3, b6);
            b6 = __builtin_fmaf(HAN63, r3, b6);
            b6 = __builtin_fmaf(-HA64, z4, b6);
            b6 = __builtin_fmaf(HAN64, r4, b6);
            b6 = __builtin_fmaf(-HA65, z5, b6);
            float z6 = __builtin_fmaf(HAN65, r5, b6);

            float w6;
            if constexpr (decltype(s6tag)::value) { w6 = z6 * s6r; }
            else { (void)s6r; w6 = z6; }
            float r6 = stage_r(w6);

            // y-update bracket, ordered by operand arrival; z6-term last-but-one
            float by = __builtin_fmaf(-HB1, z1, z1);
            by = __builtin_fmaf(HBN1, r1, by);
            by = __builtin_fmaf(-HB2, z2, by);
            by = __builtin_fmaf(HBN2, r2, by);
            by = __builtin_fmaf(-HB3, z3, by);
            by = __builtin_fmaf(HBN3, r3, by);
            by = __builtin_fmaf(-HB4, z4, by);
            by = __builtin_fmaf(HBN4, r4, by);
            by = __builtin_fmaf(-HB5, z5, by);
            by = __builtin_fmaf(HBN5, r5, by);
            by = __builtin_fmaf(-HB6, z6, by);
            z = __builtin_fmaf(HBN6, r6, by);
        };

        #pragma unroll 1
        for (int k = 0; k < NCTRL; ++k) {
            const int kn = (k < NCTRL - 1) ? (k + 1) : k;
            const float den_nx = mk_den(kn);
            const float rd_nx  = 1.0f / den_nx;
            // coordinate-change factor to next group's scaling (exact 1 for k=9)
            const float ratio = (kn != k) ? (den * rd_nx) : 1.0f;
            const float bnd = 10.0f * (float)(k + 1);

            #pragma unroll 1
            for (int iv2 = 0; iv2 < IV_PER_K; ++iv2) {
                const int iv = k * IV_PER_K + iv2;
                float t = (float)iv;   // exact

                // substeps 0..18: control index provably constant (= k)
                #pragma unroll 1
                for (int j = 0; j < NSUB - 1; ++j) {
                    substep(std::integral_constant<bool, false>{}, 1.0f);
                    t = t + 0.05f;     // bit-exact reference t accumulation
                }
                // peeled substep 19: stage-6 may cross the control boundary.
                // floor((t+h)/10)==k+1 <=> t+h >= 10(k+1) (exact near 10k)
                {
                    bool cross = (iv2 == IV_PER_K - 1) && (t + 0.05f >= bnd);
                    float s6 = cross ? ratio : 1.0f;
                    substep(std::integral_constant<bool, true>{}, s6);
                }

                float w = z * den;     // unscale for save
                if (!__builtin_isfinite(w)) { w = 0.0f; ++bad; }
                ys[(size_t)(iv + 1) * 2] = w;
            }

            // enter next group's scaled coordinates
            z   = z * ratio;
            den = den_nx;
            rd  = rd_nx;
            rebuild(num * rd);
        }

        if (bad) atomicAdd(out + (size_t)B * 222 + NSAVE, (float)bad);

    } else if (tid < B) {
        // ---- generic fallback: one thread per trajectory, both components ----
        const int b = tid;
        const float* ub = useq + (size_t)b * (NCTRL * 2);
        float A  = init[(size_t)b * 2 + 0];
        float Bc = init[(size_t)b * 2 + 1];
        float* ys = out + (size_t)b * 202;
        int bad = 0;
        {
            float wA = A, wB = Bc;
            if (!__builtin_isfinite(wA)) { wA = 0.0f; ++bad; }
            if (!__builtin_isfinite(wB)) { wB = 0.0f; ++bad; }
            ys[0] = wA; ys[1] = wB;
        }

        const float h = 0.05f;
        const float A21f = 0.161f;
        const float A31f = -0.008480655492356989f, A32f = 0.335480655492357f;
        const float A41f = 2.8971530571054935f,  A42f = -6.359448489975075f,  A43f = 4.3622954328695815f;
        const float A51f = 5.325864828439257f,   A52f = -11.748883564062828f, A53f = 7.4955393428898365f, A54f = -0.09249506636175525f;
        const float A61f = 5.86145544294642f,    A62f = -12.92096931784711f,  A63f = 8.159367898576159f,  A64f = -0.071584973281401f, A65f = -0.028269050394068383f;
        const float B1f = 0.09646076681806523f, B2f = 0.01f, B3f = 0.4798896504144996f;
        const float B4f = 1.379008574103742f,   B5f = -3.290069515436081f, B6f = 2.324710524099774f;

        auto mk_den = [&](int k, float& dA_, float& dB_) {
            float u0 = fminf(fmaxf(ub[k * 2 + 0], 0.0f), 1.0f);
            float u1 = fminf(fmaxf(ub[k * 2 + 1], 0.0f), 1.0f);
            float xA = (u0 * iptg_max) / K;
            float xB = (u1 * iptg_max) / K;
            dA_ = 1.0f + pow_np_f32(xA, n_iptg);
            dB_ = 1.0f + pow_np_f32(xB, n_iptg);
        };
        auto vf = [&](float rdA, float rdB, float As, float Bs, float& dA, float& dB) {
            float A_eff = As * rdA;
            float B_eff = Bs * rdB;
            float pB = pow_np_f32(B_eff, n_ab);
            float pA = pow_np_f32(A_eff, n_ba);
            dA = a1 / (1.0f + pB) - As;
            dB = a2 / (1.0f + pA) - Bs;
        };

        float denA, denB;
        mk_den(0, denA, denB);
        float rdenA = 1.0f / denA, rdenB = 1.0f / denB;

        #pragma unroll 1
        for (int k = 0; k < NCTRL; ++k) {
            int kn = (k < NCTRL - 1) ? (k + 1) : k;
            float denA_nx, denB_nx;
            mk_den(kn, denA_nx, denB_nx);
            float rdenA_nx = 1.0f / denA_nx, rdenB_nx = 1.0f / denB_nx;
            const float bnd = 10.0f * (float)(k + 1);

            #pragma unroll 1
            for (int iv2 = 0; iv2 < IV_PER_K; ++iv2) {
                const int iv = k * IV_PER_K + iv2;
                float t = (float)iv;
                #pragma unroll 1
                for (int j = 0; j < NSUB; ++j) {
                    bool nx = (iv2 == IV_PER_K - 1) && (j == NSUB - 1) && (t + 0.05f >= bnd);
                    float rdA6 = nx ? rdenA_nx : rdenA;
                    float rdB6 = nx ? rdenB_nx : rdenB;

                    float k1A, k1B, k2A, k2B, k3A, k3B, k4A, k4B, k5A, k5B, k6A, k6B;
                    vf(rdenA, rdenB, A, Bc, k1A, k1B);
                    vf(rdenA, rdenB, A + h * (A21f * k1A), Bc + h * (A21f * k1B), k2A, k2B);
                    vf(rdenA, rdenB, A + h * (A31f * k1A + A32f * k2A), Bc + h * (A31f * k1B + A32f * k2B), k3A, k3B);
                    vf(rdenA, rdenB, A + h * (A41f * k1A + A42f * k2A + A43f * k3A),
                                      Bc + h * (A41f * k1B + A42f * k2B + A43f * k3B), k4A, k4B);
                    vf(rdenA, rdenB, A + h * (A51f * k1A + A52f * k2A + A53f * k3A + A54f * k4A),
                                      Bc + h * (A51f * k1B + A52f * k2B + A53f * k3B + A54f * k4B), k5A, k5B);
                    vf(rdA6, rdB6,   A + h * (A61f * k1A + A62f * k2A + A63f * k3A + A64f * k4A + A65f * k5A),
                                      Bc + h * (A61f * k1B + A62f * k2B + A63f * k3B + A64f * k4B + A65f * k5B), k6A, k6B);

                    A  = A  + h * (B1f * k1A + B2f * k2A + B3f * k3A + B4f * k4A + B5f * k5A + B6f * k6A);
                    Bc = Bc + h * (B1f * k1B + B2f * k2B + B3f * k3B + B4f * k4B + B5f * k5B + B6f * k6B);
                    t  = t + h;
                }
                float wA = A, wB = Bc;
                if (!__builtin_isfinite(wA)) { wA = 0.0f; ++bad; }
                if (!__builtin_isfinite(wB)) { wB = 0.0f; ++bad; }
                ys[(size_t)(iv + 1) * 2 + 0] = wA;
                ys[(size_t)(iv + 1) * 2 + 1] = wB;
            }
            denA = denA_nx; denB = denB_nx;
            rdenA = rdenA_nx; rdenB = rdenB_nx;
        }

        if (bad) atomicAdd(out + (size_t)B * 222 + NSAVE, (float)bad);
    }
}

extern "C" void kernel_launch(void* const* d_in, const int* in_sizes, int n_in,
                              void* d_out, int out_size, void* d_ws, size_t ws_size,
                              hipStream_t stream) {
    const float* init   = (const float*)d_in[0];
    const float* useq   = (const float*)d_in[1];
    const float* params = (const float*)d_in[2];
    float* out = (float*)d_out;

    const int B = in_sizes[0] / 2;

    // zero the n_bad accumulator slot (graph-capture-safe async memset)
    hipMemsetAsync(out + (size_t)B * 222 + NSAVE, 0, sizeof(float), stream);

    const int block = 256;
    const int grid  = (2 * B + block - 1) / block;
    hipLaunchKernelGGL(toggle_tsit5_kernel, dim3(grid), dim3(block), 0, stream,
                       init, useq, params, out, B);
}

// Round 6
// 398.028 us; speedup vs baseline: 8.9325x; 1.5631x over previous
//
#include <hip/hip_runtime.h>
#include <cmath>
#include <type_traits>

#pragma clang fp contract(off)

#define NSAVE 101
#define NSUB  20
#define NCTRL 10
#define IV_PER_K 10   // 100 save intervals / 10 control intervals

// np-faithful pow for the exponents that occur (generic fallback path only).
__device__ __forceinline__ float pow_np_f32(float x, float p) {
    if (p == 2.5f) return (x * x) * sqrtf(x);
    if (p == 1.0f) return x;
    if (p == 2.0f) return x * x;
    return powf(x, p);
}

// h-premultiplied Butcher constants (double product, rounded once)
#define HCF(x) ((float)(0.05 * (x)))
__device__ constexpr float HA21 = HCF(0.161);
__device__ constexpr float HA31 = HCF(-0.008480655492356989), HA32 = HCF(0.335480655492357);
__device__ constexpr float HA41 = HCF(2.8971530571054935),  HA42 = HCF(-6.359448489975075),  HA43 = HCF(4.3622954328695815);
__device__ constexpr float HA51 = HCF(5.325864828439257),   HA52 = HCF(-11.748883564062828), HA53 = HCF(7.4955393428898365), HA54 = HCF(-0.09249506636175525);
__device__ constexpr float HA61 = HCF(5.86145544294642),    HA62 = HCF(-12.92096931784711),  HA63 = HCF(8.159367898576159),  HA64 = HCF(-0.071584973281401), HA65 = HCF(-0.028269050394068383);
__device__ constexpr float HB1 = HCF(0.09646076681806523), HB2 = HCF(0.01), HB3 = HCF(0.4798896504144996);
__device__ constexpr float HB4 = HCF(1.379008574103742),   HB5 = HCF(-3.290069515436081), HB6 = HCF(2.324710524099774);

__global__ __launch_bounds__(256) void toggle_tsit5_kernel(
    const float* __restrict__ init,
    const float* __restrict__ useq,
    const float* __restrict__ params,
    float* __restrict__ out,
    int B)
{
    const int tid = blockIdx.x * blockDim.x + threadIdx.x;

    // times = linspace(0,100,101): exact small integers in f32
    if (tid < NSAVE) out[(size_t)B * 222 + tid] = (float)tid;
    if (tid >= B) return;

    const float iptg_max = params[0];
    const float K        = params[1];
    const float n_iptg   = params[2];
    const float a1       = params[3];
    const float a2       = params[4];
    const float n_ab     = params[5];
    const float n_ba     = params[6];

    const int p = tid;
    const float* ub = useq + (size_t)p * (NCTRL * 2);

    // u clip+copy: 20 floats per trajectory, 16B aligned
    {
        float* dst = out + (size_t)B * 202 + (size_t)p * (NCTRL * 2);
        #pragma unroll
        for (int i = 0; i < 5; ++i) {
            float4 v = reinterpret_cast<const float4*>(ub)[i];
            v.x = fminf(fmaxf(v.x, 0.0f), 1.0f);
            v.y = fminf(fmaxf(v.y, 0.0f), 1.0f);
            v.z = fminf(fmaxf(v.z, 0.0f), 1.0f);
            v.w = fminf(fmaxf(v.w, 0.0f), 1.0f);
            reinterpret_cast<float4*>(dst)[i] = v;
        }
    }

    const bool special = (n_iptg == 2.0f) && (n_ab == 2.5f) && (n_ba == 1.0f);

    float* ys = out + (size_t)p * 202;
    int bad = 0;

    if (special) {
        // ---- in-thread q-form: both components in registers, coupling is
        //      register naming (no DPP, no select). Per-component arithmetic
        //      is bit-identical to R5's lane-split version. ----
        float xA0 = init[(size_t)p * 2 + 0];
        float xB0 = init[(size_t)p * 2 + 1];
        {
            float wA = xA0, wB = xB0;
            if (!__builtin_isfinite(wA)) { wA = 0.0f; ++bad; }
            if (!__builtin_isfinite(wB)) { wB = 0.0f; ++bad; }
            *reinterpret_cast<float2*>(&ys[0]) = make_float2(wA, wB);
        }

        auto mk_den = [&](int k, int c) -> float {
            float u  = fminf(fmaxf(ub[k * 2 + c], 0.0f), 1.0f);
            float xx = (u * iptg_max) / K;
            return 1.0f + xx * xx;
        };

        float denA = mk_den(0, 0), denB = mk_den(0, 1);
        float rdA = 1.0f / denA,  rdB = 1.0f / denB;
        float zA = xA0 * rdA,     zB = xB0 * rdB;

        // per-group runtime constants, per component
        float ANA21, ANA31, ANA32, ANA41, ANA42, ANA43, ANA51, ANA52, ANA53, ANA54,
              ANA61, ANA62, ANA63, ANA64, ANA65, BNA1, BNA2, BNA3, BNA4, BNA5, BNA6;
        float ANB21, ANB31, ANB32, ANB41, ANB42, ANB43, ANB51, ANB52, ANB53, ANB54,
              ANB61, ANB62, ANB63, ANB64, ANB65, BNB1, BNB2, BNB3, BNB4, BNB5, BNB6;
        auto rebuildA = [&](float RN) {
            ANA21 = HA21 * RN;
            ANA31 = HA31 * RN; ANA32 = HA32 * RN;
            ANA41 = HA41 * RN; ANA42 = HA42 * RN; ANA43 = HA43 * RN;
            ANA51 = HA51 * RN; ANA52 = HA52 * RN; ANA53 = HA53 * RN; ANA54 = HA54 * RN;
            ANA61 = HA61 * RN; ANA62 = HA62 * RN; ANA63 = HA63 * RN; ANA64 = HA64 * RN; ANA65 = HA65 * RN;
            BNA1 = HB1 * RN; BNA2 = HB2 * RN; BNA3 = HB3 * RN;
            BNA4 = HB4 * RN; BNA5 = HB5 * RN; BNA6 = HB6 * RN;
        };
        auto rebuildB = [&](float RN) {
            ANB21 = HA21 * RN;
            ANB31 = HA31 * RN; ANB32 = HA32 * RN;
            ANB41 = HA41 * RN; ANB42 = HA42 * RN; ANB43 = HA43 * RN;
            ANB51 = HA51 * RN; ANB52 = HA52 * RN; ANB53 = HA53 * RN; ANB54 = HA54 * RN;
            ANB61 = HA61 * RN; ANB62 = HA62 * RN; ANB63 = HA63 * RN; ANB64 = HA64 * RN; ANB65 = HA65 * RN;
            BNB1 = HB1 * RN; BNB2 = HB2 * RN; BNB3 = HB3 * RN;
            BNB4 = HB4 * RN; BNB5 = HB5 * RN; BNB6 = HB6 * RN;
        };
        rebuildA(a1 * rdA);
        rebuildB(a2 * rdB);

        // export pair -> reciprocals. rA (feeds zA) = rcp(1 + zB^2.5);
        // rB (feeds zB) = rcp(1 + zA). Identical expressions to R5 stage_r.
        auto stage_rA = [&](float zb) -> float {
            float pb = __builtin_fmaf(zb * zb, __builtin_amdgcn_sqrtf(zb), 1.0f);
            return __builtin_amdgcn_rcpf(pb);
        };
        auto stage_rB = [&](float za) -> float {
            return __builtin_amdgcn_rcpf(za + 1.0f);
        };

        auto substep = [&](auto s6tag, float s6A, float s6B) {
            float zA1 = zA, zB1 = zB;
            float rA1 = stage_rA(zB1);
            float rB1 = stage_rB(zA1);

            float bA2 = __builtin_fmaf(-HA21, zA1, zA1);
            float bB2 = __builtin_fmaf(-HA21, zB1, zB1);
            float zA2 = __builtin_fmaf(ANA21, rA1, bA2);
            float zB2 = __builtin_fmaf(ANB21, rB1, bB2);
            float rA2 = stage_rA(zB2);
            float rB2 = stage_rB(zA2);

            float bA3 = __builtin_fmaf(-HA31, zA1, zA1);
            bA3 = __builtin_fmaf(ANA31, rA1, bA3);
            bA3 = __builtin_fmaf(-HA32, zA2, bA3);
            float bB3 = __builtin_fmaf(-HA31, zB1, zB1);
            bB3 = __builtin_fmaf(ANB31, rB1, bB3);
            bB3 = __builtin_fmaf(-HA32, zB2, bB3);
            float zA3 = __builtin_fmaf(ANA32, rA2, bA3);
            float zB3 = __builtin_fmaf(ANB32, rB2, bB3);
            float rA3 = stage_rA(zB3);
            float rB3 = stage_rB(zA3);

            float bA4 = __builtin_fmaf(-HA41, zA1, zA1);
            bA4 = __builtin_fmaf(ANA41, rA1, bA4);
            bA4 = __builtin_fmaf(-HA42, zA2, bA4);
            bA4 = __builtin_fmaf(ANA42, rA2, bA4);
            bA4 = __builtin_fmaf(-HA43, zA3, bA4);
            float bB4 = __builtin_fmaf(-HA41, zB1, zB1);
            bB4 = __builtin_fmaf(ANB41, rB1, bB4);
            bB4 = __builtin_fmaf(-HA42, zB2, bB4);
            bB4 = __builtin_fmaf(ANB42, rB2, bB4);
            bB4 = __builtin_fmaf(-HA43, zB3, bB4);
            float zA4 = __builtin_fmaf(ANA43, rA3, bA4);
            float zB4 = __builtin_fmaf(ANB43, rB3, bB4);
            float rA4 = stage_rA(zB4);
            float rB4 = stage_rB(zA4);

            float bA5 = __builtin_fmaf(-HA51, zA1, zA1);
            bA5 = __builtin_fmaf(ANA51, rA1, bA5);
            bA5 = __builtin_fmaf(-HA52, zA2, bA5);
            bA5 = __builtin_fmaf(ANA52, rA2, bA5);
            bA5 = __builtin_fmaf(-HA53, zA3, bA5);
            bA5 = __builtin_fmaf(ANA53, rA3, bA5);
            bA5 = __builtin_fmaf(-HA54, zA4, bA5);
            float bB5 = __builtin_fmaf(-HA51, zB1, zB1);
            bB5 = __builtin_fmaf(ANB51, rB1, bB5);
            bB5 = __builtin_fmaf(-HA52, zB2, bB5);
            bB5 = __builtin_fmaf(ANB52, rB2, bB5);
            bB5 = __builtin_fmaf(-HA53, zB3, bB5);
            bB5 = __builtin_fmaf(ANB53, rB3, bB5);
            bB5 = __builtin_fmaf(-HA54, zB4, bB5);
            float zA5 = __builtin_fmaf(ANA54, rA4, bA5);
            float zB5 = __builtin_fmaf(ANB54, rB4, bB5);
            float rA5 = stage_rA(zB5);
            float rB5 = stage_rB(zA5);

            float bA6 = __builtin_fmaf(-HA61, zA1, zA1);
            bA6 = __builtin_fmaf(ANA61, rA1, bA6);
            bA6 = __builtin_fmaf(-HA62, zA2, bA6);
            bA6 = __builtin_fmaf(ANA62, rA2, bA6);
            bA6 = __builtin_fmaf(-HA63, zA3, bA6);
            bA6 = __builtin_fmaf(ANA63, rA3, bA6);
            bA6 = __builtin_fmaf(-HA64, zA4, bA6);
            bA6 = __builtin_fmaf(ANA64, rA4, bA6);
            bA6 = __builtin_fmaf(-HA65, zA5, bA6);
            float bB6 = __builtin_fmaf(-HA61, zB1, zB1);
            bB6 = __builtin_fmaf(ANB61, rB1, bB6);
            bB6 = __builtin_fmaf(-HA62, zB2, bB6);
            bB6 = __builtin_fmaf(ANB62, rB2, bB6);
            bB6 = __builtin_fmaf(-HA63, zB3, bB6);
            bB6 = __builtin_fmaf(ANB63, rB3, bB6);
            bB6 = __builtin_fmaf(-HA64, zB4, bB6);
            bB6 = __builtin_fmaf(ANB64, rB4, bB6);
            bB6 = __builtin_fmaf(-HA65, zB5, bB6);
            float zA6 = __builtin_fmaf(ANA65, rA5, bA6);
            float zB6 = __builtin_fmaf(ANB65, rB5, bB6);

            float wA6, wB6;
            if constexpr (decltype(s6tag)::value) { wA6 = zA6 * s6A; wB6 = zB6 * s6B; }
            else { (void)s6A; (void)s6B; wA6 = zA6; wB6 = zB6; }
            float rA6 = stage_rA(wB6);
            float rB6 = stage_rB(wA6);

            float byA = __builtin_fmaf(-HB1, zA1, zA1);
            byA = __builtin_fmaf(BNA1, rA1, byA);
            byA = __builtin_fmaf(-HB2, zA2, byA);
            byA = __builtin_fmaf(BNA2, rA2, byA);
            byA = __builtin_fmaf(-HB3, zA3, byA);
            byA = __builtin_fmaf(BNA3, rA3, byA);
            byA = __builtin_fmaf(-HB4, zA4, byA);
            byA = __builtin_fmaf(BNA4, rA4, byA);
            byA = __builtin_fmaf(-HB5, zA5, byA);
            byA = __builtin_fmaf(BNA5, rA5, byA);
            byA = __builtin_fmaf(-HB6, zA6, byA);
            float byB = __builtin_fmaf(-HB1, zB1, zB1);
            byB = __builtin_fmaf(BNB1, rB1, byB);
            byB = __builtin_fmaf(-HB2, zB2, byB);
            byB = __builtin_fmaf(BNB2, rB2, byB);
            byB = __builtin_fmaf(-HB3, zB3, byB);
            byB = __builtin_fmaf(BNB3, rB3, byB);
            byB = __builtin_fmaf(-HB4, zB4, byB);
            byB = __builtin_fmaf(BNB4, rB4, byB);
            byB = __builtin_fmaf(-HB5, zB5, byB);
            byB = __builtin_fmaf(BNB5, rB5, byB);
            byB = __builtin_fmaf(-HB6, zB6, byB);
            zA = __builtin_fmaf(BNA6, rA6, byA);
            zB = __builtin_fmaf(BNB6, rB6, byB);
        };

        #pragma unroll 1
        for (int k = 0; k < NCTRL; ++k) {
            const int kn = (k < NCTRL - 1) ? (k + 1) : k;
            const float denA_nx = mk_den(kn, 0), denB_nx = mk_den(kn, 1);
            const float rdA_nx = 1.0f / denA_nx, rdB_nx = 1.0f / denB_nx;
            const float ratioA = (kn != k) ? (denA * rdA_nx) : 1.0f;
            const float ratioB = (kn != k) ? (denB * rdB_nx) : 1.0f;
            const float bnd = 10.0f * (float)(k + 1);

            #pragma unroll 1
            for (int iv2 = 0; iv2 < IV_PER_K; ++iv2) {
                const int iv = k * IV_PER_K + iv2;
                float t = (float)iv;   // exact

                #pragma unroll 1
                for (int j = 0; j < NSUB - 1; ++j) {
                    substep(std::integral_constant<bool, false>{}, 1.0f, 1.0f);
                    t = t + 0.05f;     // bit-exact reference t accumulation
                }
                // peeled substep 19: stage-6 may cross the control boundary
                {
                    bool cross = (iv2 == IV_PER_K - 1) && (t + 0.05f >= bnd);
                    float s6A = cross ? ratioA : 1.0f;
                    float s6B = cross ? ratioB : 1.0f;
                    substep(std::integral_constant<bool, true>{}, s6A, s6B);
                }

                float wA = zA * denA, wB = zB * denB;
                if (!__builtin_isfinite(wA)) { wA = 0.0f; ++bad; }
                if (!__builtin_isfinite(wB)) { wB = 0.0f; ++bad; }
                *reinterpret_cast<float2*>(&ys[(size_t)(iv + 1) * 2]) = make_float2(wA, wB);
            }

            zA = zA * ratioA;
            zB = zB * ratioB;
            denA = denA_nx; rdA = rdA_nx;
            denB = denB_nx; rdB = rdB_nx;
            rebuildA(a1 * rdA);
            rebuildB(a2 * rdB);
        }

    } else {
        // ---- generic fallback: straightforward, IEEE ----
        float A  = init[(size_t)p * 2 + 0];
        float Bc = init[(size_t)p * 2 + 1];
        {
            float wA = A, wB = Bc;
            if (!__builtin_isfinite(wA)) { wA = 0.0f; ++bad; }
            if (!__builtin_isfinite(wB)) { wB = 0.0f; ++bad; }
            ys[0] = wA; ys[1] = wB;
        }

        const float h = 0.05f;
        const float A21f = 0.161f;
        const float A31f = -0.008480655492356989f, A32f = 0.335480655492357f;
        const float A41f = 2.8971530571054935f,  A42f = -6.359448489975075f,  A43f = 4.3622954328695815f;
        const float A51f = 5.325864828439257f,   A52f = -11.748883564062828f, A53f = 7.4955393428898365f, A54f = -0.09249506636175525f;
        const float A61f = 5.86145544294642f,    A62f = -12.92096931784711f,  A63f = 8.159367898576159f,  A64f = -0.071584973281401f, A65f = -0.028269050394068383f;
        const float B1f = 0.09646076681806523f, B2f = 0.01f, B3f = 0.4798896504144996f;
        const float B4f = 1.379008574103742f,   B5f = -3.290069515436081f, B6f = 2.324710524099774f;

        auto mk_den = [&](int k, float& dA_, float& dB_) {
            float u0 = fminf(fmaxf(ub[k * 2 + 0], 0.0f), 1.0f);
            float u1 = fminf(fmaxf(ub[k * 2 + 1], 0.0f), 1.0f);
            float xA = (u0 * iptg_max) / K;
            float xB = (u1 * iptg_max) / K;
            dA_ = 1.0f + pow_np_f32(xA, n_iptg);
            dB_ = 1.0f + pow_np_f32(xB, n_iptg);
        };
        auto vf = [&](float rdA, float rdB, float As, float Bs, float& dA, float& dB) {
            float A_eff = As * rdA;
            float B_eff = Bs * rdB;
            float pB = pow_np_f32(B_eff, n_ab);
            float pA = pow_np_f32(A_eff, n_ba);
            dA = a1 / (1.0f + pB) - As;
            dB = a2 / (1.0f + pA) - Bs;
        };

        float denA, denB;
        mk_den(0, denA, denB);
        float rdenA = 1.0f / denA, rdenB = 1.0f / denB;

        #pragma unroll 1
        for (int k = 0; k < NCTRL; ++k) {
            int kn = (k < NCTRL - 1) ? (k + 1) : k;
            float denA_nx, denB_nx;
            mk_den(kn, denA_nx, denB_nx);
            float rdenA_nx = 1.0f / denA_nx, rdenB_nx = 1.0f / denB_nx;
            const float bnd = 10.0f * (float)(k + 1);

            #pragma unroll 1
            for (int iv2 = 0; iv2 < IV_PER_K; ++iv2) {
                const int iv = k * IV_PER_K + iv2;
                float t = (float)iv;
                #pragma unroll 1
                for (int j = 0; j < NSUB; ++j) {
                    bool nx = (iv2 == IV_PER_K - 1) && (j == NSUB - 1) && (t + 0.05f >= bnd);
                    float rdA6 = nx ? rdenA_nx : rdenA;
                    float rdB6 = nx ? rdenB_nx : rdenB;

                    float k1A, k1B, k2A, k2B, k3A, k3B, k4A, k4B, k5A, k5B, k6A, k6B;
                    vf(rdenA, rdenB, A, Bc, k1A, k1B);
                    vf(rdenA, rdenB, A + h * (A21f * k1A), Bc + h * (A21f * k1B), k2A, k2B);
                    vf(rdenA, rdenB, A + h * (A31f * k1A + A32f * k2A), Bc + h * (A31f * k1B + A32f * k2B), k3A, k3B);
                    vf(rdenA, rdenB, A + h * (A41f * k1A + A42f * k2A + A43f * k3A),
                                      Bc + h * (A41f * k1B + A42f * k2B + A43f * k3B), k4A, k4B);
                    vf(rdenA, rdenB, A + h * (A51f * k1A + A52f * k2A + A53f * k3A + A54f * k4A),
                                      Bc + h * (A51f * k1B + A52f * k2B + A53f * k3B + A54f * k4B), k5A, k5B);
                    vf(rdA6, rdB6,   A + h * (A61f * k1A + A62f * k2A + A63f * k3A + A64f * k4A + A65f * k5A),
                                      Bc + h * (A61f * k1B + A62f * k2B + A63f * k3B + A64f * k4B + A65f * k5B), k6A, k6B);

                    A  = A  + h * (B1f * k1A + B2f * k2A + B3f * k3A + B4f * k4A + B5f * k5A + B6f * k6A);
                    Bc = Bc + h * (B1f * k1B + B2f * k2B + B3f * k3B + B4f * k4B + B5f * k5B + B6f * k6B);
                    t  = t + h;
                }
                float wA = A, wB = Bc;
                if (!__builtin_isfinite(wA)) { wA = 0.0f; ++bad; }
                if (!__builtin_isfinite(wB)) { wB = 0.0f; ++bad; }
                ys[(size_t)(iv + 1) * 2 + 0] = wA;
                ys[(size_t)(iv + 1) * 2 + 1] = wB;
            }
            denA = denA_nx; denB = denB_nx;
            rdenA = rdenA_nx; rdenB = rdenB_nx;
        }
    }

    if (bad) atomicAdd(out + (size_t)B * 222 + NSAVE, (float)bad);
}

extern "C" void kernel_launch(void* const* d_in, const int* in_sizes, int n_in,
                              void* d_out, int out_size, void* d_ws, size_t ws_size,
                              hipStream_t stream) {
    const float* init   = (const float*)d_in[0];
    const float* useq   = (const float*)d_in[1];
    const float* params = (const float*)d_in[2];
    float* out = (float*)d_out;

    const int B = in_sizes[0] / 2;

    // zero the n_bad accumulator slot (graph-capture-safe async memset)
    hipMemsetAsync(out + (size_t)B * 222 + NSAVE, 0, sizeof(float), stream);

    const int block = 256;
    const int grid  = (B + block - 1) / block;
    hipLaunchKernelGGL(toggle_tsit5_kernel, dim3(grid), dim3(block), 0, stream,
                       init, useq, params, out, B);
}

// Round 8
// 390.765 us; speedup vs baseline: 9.0986x; 1.0186x over previous
//
#include <hip/hip_runtime.h>
#include <cmath>
#include <type_traits>

#pragma clang fp contract(off)

#define NSAVE 101
#define NSUB  20
#define NCTRL 10
#define IV_PER_K 10   // 100 save intervals / 10 control intervals

typedef float v2f __attribute__((ext_vector_type(2)));

// Packed f32 math via LLVM vector intrinsics: llvm.fma.v2f32 / fmul v2f32
// lower to v_pk_fma_f32 / v_pk_mul_f32 on gfx90a+ (ISel patterns), with
// per-element IEEE semantics — bit-identical to scalar fmaf/mul per half.
// (R7's hand-written VOP3P asm had wrong operand-select semantics -> blowup.)
__device__ __forceinline__ v2f pk_fma(v2f a, v2f b, v2f c) {
    return __builtin_elementwise_fma(a, b, c);
}
__device__ __forceinline__ v2f pk_mul(v2f a, v2f b) {
    return a * b;
}

// np-faithful pow for the exponents that occur (generic fallback path only).
__device__ __forceinline__ float pow_np_f32(float x, float p) {
    if (p == 2.5f) return (x * x) * sqrtf(x);
    if (p == 1.0f) return x;
    if (p == 2.0f) return x * x;
    return powf(x, p);
}

// h-premultiplied Butcher constants (double product, rounded once)
#define HCF(x) ((float)(0.05 * (x)))
__device__ constexpr float HA21 = HCF(0.161);
__device__ constexpr float HA31 = HCF(-0.008480655492356989), HA32 = HCF(0.335480655492357);
__device__ constexpr float HA41 = HCF(2.8971530571054935),  HA42 = HCF(-6.359448489975075),  HA43 = HCF(4.3622954328695815);
__device__ constexpr float HA51 = HCF(5.325864828439257),   HA52 = HCF(-11.748883564062828), HA53 = HCF(7.4955393428898365), HA54 = HCF(-0.09249506636175525);
__device__ constexpr float HA61 = HCF(5.86145544294642),    HA62 = HCF(-12.92096931784711),  HA63 = HCF(8.159367898576159),  HA64 = HCF(-0.071584973281401), HA65 = HCF(-0.028269050394068383);
__device__ constexpr float HB1 = HCF(0.09646076681806523), HB2 = HCF(0.01), HB3 = HCF(0.4798896504144996);
__device__ constexpr float HB4 = HCF(1.379008574103742),   HB5 = HCF(-3.290069515436081), HB6 = HCF(2.324710524099774);

__global__ __launch_bounds__(256, 1) void toggle_tsit5_kernel(
    const float* __restrict__ init,
    const float* __restrict__ useq,
    const float* __restrict__ params,
    float* __restrict__ out,
    int B)
{
    const int tid = blockIdx.x * blockDim.x + threadIdx.x;

    // times = linspace(0,100,101): exact small integers in f32
    if (tid < NSAVE) out[(size_t)B * 222 + tid] = (float)tid;
    if (tid >= B) return;

    const float iptg_max = params[0];
    const float K        = params[1];
    const float n_iptg   = params[2];
    const float a1       = params[3];
    const float a2       = params[4];
    const float n_ab     = params[5];
    const float n_ba     = params[6];

    const int p = tid;
    const float* ub = useq + (size_t)p * (NCTRL * 2);

    // u clip+copy: 20 floats per trajectory, 16B aligned
    {
        float* dst = out + (size_t)B * 202 + (size_t)p * (NCTRL * 2);
        #pragma unroll
        for (int i = 0; i < 5; ++i) {
            float4 v = reinterpret_cast<const float4*>(ub)[i];
            v.x = fminf(fmaxf(v.x, 0.0f), 1.0f);
            v.y = fminf(fmaxf(v.y, 0.0f), 1.0f);
            v.z = fminf(fmaxf(v.z, 0.0f), 1.0f);
            v.w = fminf(fmaxf(v.w, 0.0f), 1.0f);
            reinterpret_cast<float4*>(dst)[i] = v;
        }
    }

    const bool special = (n_iptg == 2.0f) && (n_ab == 2.5f) && (n_ba == 1.0f);

    float* ys = out + (size_t)p * 202;
    int bad = 0;

    if (special) {
        // ---- packed in-thread q-form: z = (zA, zB) in a VGPR pair; all
        //      bracket/update FMAs are vector-fma (pk-packable). Per-half
        //      arithmetic is bit-identical to the R6 scalar version. ----
        float xA0 = init[(size_t)p * 2 + 0];
        float xB0 = init[(size_t)p * 2 + 1];
        {
            float wA = xA0, wB = xB0;
            if (!__builtin_isfinite(wA)) { wA = 0.0f; ++bad; }
            if (!__builtin_isfinite(wB)) { wB = 0.0f; ++bad; }
            *reinterpret_cast<float2*>(&ys[0]) = make_float2(wA, wB);
        }

        auto mk_den = [&](int k, int c) -> float {
            float u  = fminf(fmaxf(ub[k * 2 + c], 0.0f), 1.0f);
            float xx = (u * iptg_max) / K;
            return 1.0f + xx * xx;
        };

        float denA = mk_den(0, 0), denB = mk_den(0, 1);
        float rdA = 1.0f / denA,  rdB = 1.0f / denB;
        v2f z = { xA0 * rdA, xB0 * rdB };

        // broadcast coefficient pairs (compile-time values)
        const v2f nHA21 = {-HA21, -HA21};
        const v2f nHA31 = {-HA31, -HA31}, nHA32 = {-HA32, -HA32};
        const v2f nHA41 = {-HA41, -HA41}, nHA42 = {-HA42, -HA42}, nHA43 = {-HA43, -HA43};
        const v2f nHA51 = {-HA51, -HA51}, nHA52 = {-HA52, -HA52}, nHA53 = {-HA53, -HA53}, nHA54 = {-HA54, -HA54};
        const v2f nHA61 = {-HA61, -HA61}, nHA62 = {-HA62, -HA62}, nHA63 = {-HA63, -HA63}, nHA64 = {-HA64, -HA64}, nHA65 = {-HA65, -HA65};
        const v2f nHB1 = {-HB1, -HB1}, nHB2 = {-HB2, -HB2}, nHB3 = {-HB3, -HB3};
        const v2f nHB4 = {-HB4, -HB4}, nHB5 = {-HB5, -HB5}, nHB6 = {-HB6, -HB6};

        // per-group coefficient pairs: AN_ij = {HA_ij*RNA, HA_ij*RNB}
        v2f AN21, AN31, AN32, AN41, AN42, AN43, AN51, AN52, AN53, AN54,
            AN61, AN62, AN63, AN64, AN65, BN1, BN2, BN3, BN4, BN5, BN6;
        auto rebuild = [&](float RNA, float RNB) {
            AN21 = (v2f){HA21 * RNA, HA21 * RNB};
            AN31 = (v2f){HA31 * RNA, HA31 * RNB}; AN32 = (v2f){HA32 * RNA, HA32 * RNB};
            AN41 = (v2f){HA41 * RNA, HA41 * RNB}; AN42 = (v2f){HA42 * RNA, HA42 * RNB}; AN43 = (v2f){HA43 * RNA, HA43 * RNB};
            AN51 = (v2f){HA51 * RNA, HA51 * RNB}; AN52 = (v2f){HA52 * RNA, HA52 * RNB}; AN53 = (v2f){HA53 * RNA, HA53 * RNB}; AN54 = (v2f){HA54 * RNA, HA54 * RNB};
            AN61 = (v2f){HA61 * RNA, HA61 * RNB}; AN62 = (v2f){HA62 * RNA, HA62 * RNB}; AN63 = (v2f){HA63 * RNA, HA63 * RNB}; AN64 = (v2f){HA64 * RNA, HA64 * RNB}; AN65 = (v2f){HA65 * RNA, HA65 * RNB};
            BN1 = (v2f){HB1 * RNA, HB1 * RNB}; BN2 = (v2f){HB2 * RNA, HB2 * RNB}; BN3 = (v2f){HB3 * RNA, HB3 * RNB};
            BN4 = (v2f){HB4 * RNA, HB4 * RNB}; BN5 = (v2f){HB5 * RNA, HB5 * RNB}; BN6 = (v2f){HB6 * RNA, HB6 * RNB};
        };
        rebuild(a1 * rdA, a2 * rdB);

        // exports: r.x (feeds A-half) = rcp(1 + zB^2.5); r.y = rcp(1 + zA)
        auto stage_r = [&](v2f zi) -> v2f {
            float zb = zi.y;
            float qB = __builtin_fmaf(zb * zb, __builtin_amdgcn_sqrtf(zb), 1.0f);
            float pA = zi.x + 1.0f;
            v2f r;
            r.x = __builtin_amdgcn_rcpf(qB);
            r.y = __builtin_amdgcn_rcpf(pA);
            return r;
        };

        auto substep = [&](auto s6tag, v2f s6) {
            v2f z1 = z;
            v2f r1 = stage_r(z1);

            v2f b2 = pk_fma(nHA21, z1, z1);
            v2f z2 = pk_fma(AN21, r1, b2);
            v2f r2 = stage_r(z2);

            v2f b3 = pk_fma(nHA31, z1, z1);
            b3 = pk_fma(AN31, r1, b3);
            b3 = pk_fma(nHA32, z2, b3);
            v2f z3 = pk_fma(AN32, r2, b3);
            v2f r3 = stage_r(z3);

            v2f b4 = pk_fma(nHA41, z1, z1);
            b4 = pk_fma(AN41, r1, b4);
            b4 = pk_fma(nHA42, z2, b4);
            b4 = pk_fma(AN42, r2, b4);
            b4 = pk_fma(nHA43, z3, b4);
            v2f z4 = pk_fma(AN43, r3, b4);
            v2f r4 = stage_r(z4);

            v2f b5 = pk_fma(nHA51, z1, z1);
            b5 = pk_fma(AN51, r1, b5);
            b5 = pk_fma(nHA52, z2, b5);
            b5 = pk_fma(AN52, r2, b5);
            b5 = pk_fma(nHA53, z3, b5);
            b5 = pk_fma(AN53, r3, b5);
            b5 = pk_fma(nHA54, z4, b5);
            v2f z5 = pk_fma(AN54, r4, b5);
            v2f r5 = stage_r(z5);

            v2f b6 = pk_fma(nHA61, z1, z1);
            b6 = pk_fma(AN61, r1, b6);
            b6 = pk_fma(nHA62, z2, b6);
            b6 = pk_fma(AN62, r2, b6);
            b6 = pk_fma(nHA63, z3, b6);
            b6 = pk_fma(AN63, r3, b6);
            b6 = pk_fma(nHA64, z4, b6);
            b6 = pk_fma(AN64, r4, b6);
            b6 = pk_fma(nHA65, z5, b6);
            v2f z6 = pk_fma(AN65, r5, b6);

            v2f w6 = z6;
            if constexpr (decltype(s6tag)::value) w6 = pk_mul(z6, s6);
            v2f r6 = stage_r(w6);

            v2f by = pk_fma(nHB1, z1, z1);
            by = pk_fma(BN1, r1, by);
            by = pk_fma(nHB2, z2, by);
            by = pk_fma(BN2, r2, by);
            by = pk_fma(nHB3, z3, by);
            by = pk_fma(BN3, r3, by);
            by = pk_fma(nHB4, z4, by);
            by = pk_fma(BN4, r4, by);
            by = pk_fma(nHB5, z5, by);
            by = pk_fma(BN5, r5, by);
            by = pk_fma(nHB6, z6, by);
            z = pk_fma(BN6, r6, by);
        };

        #pragma unroll 1
        for (int k = 0; k < NCTRL; ++k) {
            const int kn = (k < NCTRL - 1) ? (k + 1) : k;
            const float denA_nx = mk_den(kn, 0), denB_nx = mk_den(kn, 1);
            const float rdA_nx = 1.0f / denA_nx, rdB_nx = 1.0f / denB_nx;
            const float ratioA = (kn != k) ? (denA * rdA_nx) : 1.0f;
            const float ratioB = (kn != k) ? (denB * rdB_nx) : 1.0f;
            const float bnd = 10.0f * (float)(k + 1);

            #pragma unroll 1
            for (int iv2 = 0; iv2 < IV_PER_K; ++iv2) {
                const int iv = k * IV_PER_K + iv2;
                float t = (float)iv;   // exact

                #pragma unroll 1
                for (int j = 0; j < NSUB - 1; ++j) {
                    substep(std::integral_constant<bool, false>{}, (v2f){1.0f, 1.0f});
                    t = t + 0.05f;     // bit-exact reference t accumulation
                }
                // peeled substep 19: stage-6 may cross the control boundary
                {
                    bool cross = (iv2 == IV_PER_K - 1) && (t + 0.05f >= bnd);
                    v2f s6 = cross ? (v2f){ratioA, ratioB} : (v2f){1.0f, 1.0f};
                    substep(std::integral_constant<bool, true>{}, s6);
                }

                float wA = z.x * denA, wB = z.y * denB;
                if (!__builtin_isfinite(wA)) { wA = 0.0f; ++bad; }
                if (!__builtin_isfinite(wB)) { wB = 0.0f; ++bad; }
                *reinterpret_cast<float2*>(&ys[(size_t)(iv + 1) * 2]) = make_float2(wA, wB);
            }

            z = pk_mul(z, (v2f){ratioA, ratioB});
            denA = denA_nx; rdA = rdA_nx;
            denB = denB_nx; rdB = rdB_nx;
            rebuild(a1 * rdA, a2 * rdB);
        }

    } else {
        // ---- generic fallback: straightforward, IEEE ----
        float A  = init[(size_t)p * 2 + 0];
        float Bc = init[(size_t)p * 2 + 1];
        {
            float wA = A, wB = Bc;
            if (!__builtin_isfinite(wA)) { wA = 0.0f; ++bad; }
            if (!__builtin_isfinite(wB)) { wB = 0.0f; ++bad; }
            ys[0] = wA; ys[1] = wB;
        }

        const float h = 0.05f;
        const float A21f = 0.161f;
        const float A31f = -0.008480655492356989f, A32f = 0.335480655492357f;
        const float A41f = 2.8971530571054935f,  A42f = -6.359448489975075f,  A43f = 4.3622954328695815f;
        const float A51f = 5.325864828439257f,   A52f = -11.748883564062828f, A53f = 7.4955393428898365f, A54f = -0.09249506636175525f;
        const float A61f = 5.86145544294642f,    A62f = -12.92096931784711f,  A63f = 8.159367898576159f,  A64f = -0.071584973281401f, A65f = -0.028269050394068383f;
        const float B1f = 0.09646076681806523f, B2f = 0.01f, B3f = 0.4798896504144996f;
        const float B4f = 1.379008574103742f,   B5f = -3.290069515436081f, B6f = 2.324710524099774f;

        auto mk_den = [&](int k, float& dA_, float& dB_) {
            float u0 = fminf(fmaxf(ub[k * 2 + 0], 0.0f), 1.0f);
            float u1 = fminf(fmaxf(ub[k * 2 + 1], 0.0f), 1.0f);
            float xA = (u0 * iptg_max) / K;
            float xB = (u1 * iptg_max) / K;
            dA_ = 1.0f + pow_np_f32(xA, n_iptg);
            dB_ = 1.0f + pow_np_f32(xB, n_iptg);
        };
        auto vf = [&](float rdA, float rdB, float As, float Bs, float& dA, float& dB) {
            float A_eff = As * rdA;
            float B_eff = Bs * rdB;
            float pB = pow_np_f32(B_eff, n_ab);
            float pA = pow_np_f32(A_eff, n_ba);
            dA = a1 / (1.0f + pB) - As;
            dB = a2 / (1.0f + pA) - Bs;
        };

        float denA, denB;
        mk_den(0, denA, denB);
        float rdenA = 1.0f / denA, rdenB = 1.0f / denB;

        #pragma unroll 1
        for (int k = 0; k < NCTRL; ++k) {
            int kn = (k < NCTRL - 1) ? (k + 1) : k;
            float denA_nx, denB_nx;
            mk_den(kn, denA_nx, denB_nx);
            float rdenA_nx = 1.0f / denA_nx, rdenB_nx = 1.0f / denB_nx;
            const float bnd = 10.0f * (float)(k + 1);

            #pragma unroll 1
            for (int iv2 = 0; iv2 < IV_PER_K; ++iv2) {
                const int iv = k * IV_PER_K + iv2;
                float t = (float)iv;
                #pragma unroll 1
                for (int j = 0; j < NSUB; ++j) {
                    bool nx = (iv2 == IV_PER_K - 1) && (j == NSUB - 1) && (t + 0.05f >= bnd);
                    float rdA6 = nx ? rdenA_nx : rdenA;
                    float rdB6 = nx ? rdenB_nx : rdenB;

                    float k1A, k1B, k2A, k2B, k3A, k3B, k4A, k4B, k5A, k5B, k6A, k6B;
                    vf(rdenA, rdenB, A, Bc, k1A, k1B);
                    vf(rdenA, rdenB, A + h * (A21f * k1A), Bc + h * (A21f * k1B), k2A, k2B);
                    vf(rdenA, rdenB, A + h * (A31f * k1A + A32f * k2A), Bc + h * (A31f * k1B + A32f * k2B), k3A, k3B);
                    vf(rdenA, rdenB, A + h * (A41f * k1A + A42f * k2A + A43f * k3A),
                                      Bc + h * (A41f * k1B + A42f * k2B + A43f * k3B), k4A, k4B);
                    vf(rdenA, rdenB, A + h * (A51f * k1A + A52f * k2A + A53f * k3A + A54f * k4A),
                                      Bc + h * (A51f * k1B + A52f * k2B + A53f * k3B + A54f * k4B), k5A, k5B);
                    vf(rdA6, rdB6,   A + h * (A61f * k1A + A62f * k2A + A63f * k3A + A64f * k4A + A65f * k5A),
                                      Bc + h * (A61f * k1B + A62f * k2B + A63f * k3B + A64f * k4B + A65f * k5B), k6A, k6B);

                    A  = A  + h * (B1f * k1A + B2f * k2A + B3f * k3A + B4f * k4A + B5f * k5A + B6f * k6A);
                    Bc = Bc + h * (B1f * k1B + B2f * k2B + B3f * k3B + B4f * k4B + B5f * k5B + B6f * k6B);
                    t  = t + h;
                }
                float wA = A, wB = Bc;
                if (!__builtin_isfinite(wA)) { wA = 0.0f; ++bad; }
                if (!__builtin_isfinite(wB)) { wB = 0.0f; ++bad; }
                ys[(size_t)(iv + 1) * 2 + 0] = wA;
                ys[(size_t)(iv + 1) * 2 + 1] = wB;
            }
            denA = denA_nx; denB = denB_nx;
            rdenA = rdenA_nx; rdenB = rdenB_nx;
        }
    }

    if (bad) atomicAdd(out + (size_t)B * 222 + NSAVE, (float)bad);
}

extern "C" void kernel_launch(void* const* d_in, const int* in_sizes, int n_in,
                              void* d_out, int out_size, void* d_ws, size_t ws_size,
                              hipStream_t stream) {
    const float* init   = (const float*)d_in[0];
    const float* useq   = (const float*)d_in[1];
    const float* params = (const float*)d_in[2];
    float* out = (float*)d_out;

    const int B = in_sizes[0] / 2;

    // zero the n_bad accumulator slot (graph-capture-safe async memset)
    hipMemsetAsync(out + (size_t)B * 222 + NSAVE, 0, sizeof(float), stream);

    const int block = 256;
    const int grid  = (B + block - 1) / block;
    hipLaunchKernelGGL(toggle_tsit5_kernel, dim3(grid), dim3(block), 0, stream,
                       init, useq, params, out, B);
}